// Round 11
// baseline (777.079 us; speedup 1.0000x reference)
//
#include <hip/hip_runtime.h>
#include <hip/hip_bf16.h>
#include <math.h>

#define SEQ_LEN 1024
#define BATCH_N 8
#define DMODEL 256
#define DINNER 512
#define DSTATE 16
#define DTRANK 16
#define ROWS (BATCH_N * SEQ_LEN)   // 8192
#define NCHUNK 64
#define CHUNK (SEQ_LEN / NCHUNK)   // 16
#define BD 8                       // d-channels per block (scan)

typedef unsigned short u16;
typedef u16 u16x8 __attribute__((ext_vector_type(8)));
typedef short bf16x8 __attribute__((ext_vector_type(8)));
typedef float f32x4 __attribute__((ext_vector_type(4)));

__device__ __forceinline__ float siluf(float x) { return x / (1.f + expf(-x)); }
__device__ __forceinline__ float softplusf(float x) {
    return fmaxf(x, 0.f) + log1pf(expf(-fabsf(x)));
}
// fast-math variants (scan-only; ~2ulp) — round-5 measured-good (-7.4us).
__device__ __forceinline__ float fexpf(float x) { return __expf(x); }
__device__ __forceinline__ float softplus_fast(float x) {
    return fmaxf(x, 0.f) + __logf(1.f + __expf(-fabsf(x)));
}
__device__ __forceinline__ float silu_fast(float x) {
    return x * __builtin_amdgcn_rcpf(1.f + __expf(-x));
}
__device__ __forceinline__ u16 bf16_rne(float x) {
    unsigned u = __builtin_bit_cast(unsigned, x);
    return (u16)((u + 0x7FFFu + ((u >> 16) & 1u)) >> 16);
}
__device__ __forceinline__ void cvt_hl(float x, u16& h, u16& l) {
    unsigned u = __builtin_bit_cast(unsigned, x);
    unsigned hb = (u + 0x7FFFu + ((u >> 16) & 1u)) >> 16;
    h = (u16)hb;
    float hf = __builtin_bit_cast(float, hb << 16);
    l = bf16_rne(x - hf);
}
__device__ __forceinline__ float pair_f(u16 h, u16 l) {
    return __builtin_bit_cast(float, (unsigned)h << 16) +
           __builtin_bit_cast(float, (unsigned)l << 16);
}
// fragment-swizzled activation address: tensor [R rows][Kc cols] stored as
// [Kc/32][R][32]; elem (row,c) at ((c>>5)*R + row)*32 + (c&31)
__device__ __forceinline__ size_t swa(int R, int row, int c) {
    return ((size_t)(c >> 5) * R + row) * 32 + (c & 31);
}

// x fp32 [8192][64] -> swizzled bf16 hi/lo pairs
__global__ __launch_bounds__(256) void cvt_x_swz(
    const float* __restrict__ x, u16* __restrict__ dh, u16* __restrict__ dl)
{
    int i = blockIdx.x * 256 + threadIdx.x;   // < ROWS*64
    int row = i >> 6, c = i & 63;
    u16 h, l;
    cvt_hl(x[i], h, l);
    size_t sw = swa(ROWS, row, c);
    dh[sw] = h;
    dl[sw] = l;
}

// all 4 weight tensors -> fragment-swizzled single bf16 ([k/32][Npad][32])
// segments: Wp(256x64), W_in 4x(1024x256), W_x 4x(48->64 x 512), W_out 4x(256x512)
#define CWT (16384 + 4 * 262144 + 4 * 32768 + 4 * 131072)   // 1720320
__global__ __launch_bounds__(256) void cvt_w_swz(
    const float* __restrict__ Wp, const float* __restrict__ W_in,
    const float* __restrict__ W_x, const float* __restrict__ W_out,
    u16* __restrict__ Wpb, u16* __restrict__ Wib,
    u16* __restrict__ Wxb, u16* __restrict__ Wob)
{
    long i = (long)blockIdx.x * 256 + threadIdx.x;
    if (i >= CWT) return;
    if (i < 16384) {                       // Wp: N=256 K=64
        int n = (int)(i >> 6), k = (int)(i & 63);
        Wpb[((k >> 5) * 256 + n) * 32 + (k & 31)] = bf16_rne(Wp[n * 64 + k]);
        return;
    }
    i -= 16384;
    if (i < 4 * 262144) {                  // W_in: N=1024 K=256
        int l = (int)(i >> 18), r = (int)(i & 262143);
        int n = r >> 8, k = r & 255;
        Wib[l * 262144 + ((k >> 5) * 1024 + n) * 32 + (k & 31)] =
            bf16_rne(W_in[l * 262144 + n * 256 + k]);
        return;
    }
    i -= 4 * 262144;
    if (i < 4 * 32768) {                   // W_x: N=48 (pad 64) K=512
        int l = (int)(i >> 15), r = (int)(i & 32767);
        int n = r >> 9, k = r & 511;
        float v = (n < 48) ? W_x[l * 48 * 512 + n * 512 + k] : 0.f;
        Wxb[l * 32768 + ((k >> 5) * 64 + n) * 32 + (k & 31)] = bf16_rne(v);
        return;
    }
    i -= 4 * 32768;
    {                                      // W_out: N=256 K=512
        int l = (int)(i >> 17), r = (int)(i & 131071);
        int n = r >> 9, k = r & 511;
        Wob[l * 131072 + ((k >> 5) * 256 + n) * 32 + (k & 31)] =
            bf16_rne(W_out[l * 131072 + n * 512 + k]);
    }
}

// ---------------------------------------------------------------------------
// LDS-free MFMA GEMM on fragment-swizzled operands (round-11 measured-good).
// ---------------------------------------------------------------------------
template<int EPI>
__global__ __launch_bounds__(256) void gemm_sw(
    const u16* __restrict__ Ah, const u16* __restrict__ Al,
    const u16* __restrict__ B,
    const float* __restrict__ bias, float* __restrict__ C,
    u16* __restrict__ Ch, u16* __restrict__ Cl,
    int M, int N, int Npad, int K, int ldc)
{
    const int tid  = threadIdx.x;
    const int wave = tid >> 6, lane = tid & 63;
    const int bm   = blockIdx.y * 64, bn = blockIdx.x * 64;
    const int wm   = (wave >> 1) * 32, wn = (wave & 1) * 32;
    const int fr   = lane & 15, quad = lane >> 4;

    f32x4 acc[2][2];
#pragma unroll
    for (int i = 0; i < 2; i++)
#pragma unroll
        for (int j = 0; j < 2; j++) acc[i][j] = (f32x4){0.f, 0.f, 0.f, 0.f};

    const size_t a0 = (size_t)(bm + wm + fr) * 32 + quad * 8;
    const size_t a1 = a0 + 16 * 32;
    const size_t b0 = (size_t)(bn + wn + fr) * 32 + quad * 8;
    const size_t b1 = b0 + 16 * 32;
    const size_t astep = (size_t)M * 32;
    const size_t bstep = (size_t)Npad * 32;

    const u16* pah = Ah;
    const u16* pal = Al;
    const u16* pb  = B;
#pragma unroll 2
    for (int k0 = 0; k0 < K; k0 += 32) {
        bf16x8 ah0 = *(const bf16x8*)(pah + a0);
        bf16x8 ah1 = *(const bf16x8*)(pah + a1);
        bf16x8 al0 = *(const bf16x8*)(pal + a0);
        bf16x8 al1 = *(const bf16x8*)(pal + a1);
        bf16x8 bv0 = *(const bf16x8*)(pb + b0);
        bf16x8 bv1 = *(const bf16x8*)(pb + b1);
        acc[0][0] = __builtin_amdgcn_mfma_f32_16x16x32_bf16(ah0, bv0, acc[0][0], 0, 0, 0);
        acc[0][0] = __builtin_amdgcn_mfma_f32_16x16x32_bf16(al0, bv0, acc[0][0], 0, 0, 0);
        acc[0][1] = __builtin_amdgcn_mfma_f32_16x16x32_bf16(ah0, bv1, acc[0][1], 0, 0, 0);
        acc[0][1] = __builtin_amdgcn_mfma_f32_16x16x32_bf16(al0, bv1, acc[0][1], 0, 0, 0);
        acc[1][0] = __builtin_amdgcn_mfma_f32_16x16x32_bf16(ah1, bv0, acc[1][0], 0, 0, 0);
        acc[1][0] = __builtin_amdgcn_mfma_f32_16x16x32_bf16(al1, bv0, acc[1][0], 0, 0, 0);
        acc[1][1] = __builtin_amdgcn_mfma_f32_16x16x32_bf16(ah1, bv1, acc[1][1], 0, 0, 0);
        acc[1][1] = __builtin_amdgcn_mfma_f32_16x16x32_bf16(al1, bv1, acc[1][1], 0, 0, 0);
        pah += astep; pal += astep; pb += bstep;
    }

    // C/D layout (m89-verified): row = quad*4 + reg, col = fr within 16x16 frag
#pragma unroll
    for (int i = 0; i < 2; i++) {
        const int r0 = bm + wm + 16 * i + quad * 4;
#pragma unroll
        for (int reg = 0; reg < 4; reg++) {
            const int row = r0 + reg;
#pragma unroll
            for (int j = 0; j < 2; j++) {
                const int col = bn + wn + 16 * j + fr;
                if (col < N) {
                    float v = acc[i][j][reg];
                    if (bias) v += bias[col];
                    if (EPI == 0) {
                        C[(size_t)row * ldc + col] = v;
                    } else {
                        u16 h, l;
                        cvt_hl(v, h, l);
                        size_t sw = swa(M, row, col);
                        Ch[sw] = h;
                        Cl[sw] = l;
                    }
                }
            }
        }
    }
}

// ---------------------------------------------------------------------------
// Wide variant: 64x128 block (4 waves 2x2, each 32x64 = 2x4 frags).
// ---------------------------------------------------------------------------
__global__ __launch_bounds__(256) void gemm_sw128(
    const u16* __restrict__ Ah, const u16* __restrict__ Al,
    const u16* __restrict__ B, float* __restrict__ C,
    int M, int Npad, int K, int ldc)
{
    const int tid  = threadIdx.x;
    const int wave = tid >> 6, lane = tid & 63;
    const int bm   = blockIdx.y * 64, bn = blockIdx.x * 128;
    const int wm   = (wave >> 1) * 32, wn = (wave & 1) * 64;
    const int fr   = lane & 15, quad = lane >> 4;

    f32x4 acc[2][4];
#pragma unroll
    for (int i = 0; i < 2; i++)
#pragma unroll
        for (int j = 0; j < 4; j++) acc[i][j] = (f32x4){0.f, 0.f, 0.f, 0.f};

    const size_t a0 = (size_t)(bm + wm + fr) * 32 + quad * 8;
    const size_t a1 = a0 + 16 * 32;
    size_t bofs[4];
#pragma unroll
    for (int j = 0; j < 4; j++)
        bofs[j] = (size_t)(bn + wn + 16 * j + fr) * 32 + quad * 8;
    const size_t astep = (size_t)M * 32;
    const size_t bstep = (size_t)Npad * 32;

    const u16* pah = Ah;
    const u16* pal = Al;
    const u16* pb  = B;
    for (int k0 = 0; k0 < K; k0 += 32) {
        bf16x8 ah0 = *(const bf16x8*)(pah + a0);
        bf16x8 ah1 = *(const bf16x8*)(pah + a1);
        bf16x8 al0 = *(const bf16x8*)(pal + a0);
        bf16x8 al1 = *(const bf16x8*)(pal + a1);
        bf16x8 bv[4];
#pragma unroll
        for (int j = 0; j < 4; j++) bv[j] = *(const bf16x8*)(pb + bofs[j]);
#pragma unroll
        for (int j = 0; j < 4; j++) {
            acc[0][j] = __builtin_amdgcn_mfma_f32_16x16x32_bf16(ah0, bv[j], acc[0][j], 0, 0, 0);
            acc[0][j] = __builtin_amdgcn_mfma_f32_16x16x32_bf16(al0, bv[j], acc[0][j], 0, 0, 0);
            acc[1][j] = __builtin_amdgcn_mfma_f32_16x16x32_bf16(ah1, bv[j], acc[1][j], 0, 0, 0);
            acc[1][j] = __builtin_amdgcn_mfma_f32_16x16x32_bf16(al1, bv[j], acc[1][j], 0, 0, 0);
        }
        pah += astep; pal += astep; pb += bstep;
    }

#pragma unroll
    for (int i = 0; i < 2; i++) {
        const int r0 = bm + wm + 16 * i + quad * 4;
#pragma unroll
        for (int reg = 0; reg < 4; reg++) {
            float* crow = C + (size_t)(r0 + reg) * ldc;
#pragma unroll
            for (int j = 0; j < 4; j++)
                crow[bn + wn + 16 * j + fr] = acc[i][j][reg];
        }
    }
}

// ---------------------------------------------------------------------------
// xdbl GEMM specialization (round-7 measured-good): M=8192, N=48 (Npad=64),
// K=512; 32rx64c blocks, grid 256.
// ---------------------------------------------------------------------------
__global__ __launch_bounds__(256) void gemm_xdbl(
    const u16* __restrict__ Ah, const u16* __restrict__ Al,
    const u16* __restrict__ B, float* __restrict__ C)
{
    const int tid  = threadIdx.x;
    const int wave = tid >> 6, lane = tid & 63;
    const int bm   = blockIdx.x * 32;
    const int wr   = (wave >> 1) * 16;    // row-half within the 32-row tile
    const int wc   = (wave & 1) * 32;     // col-half within the 64-col tile
    const int fr   = lane & 15, quad = lane >> 4;

    f32x4 acc[2];
    acc[0] = (f32x4){0.f, 0.f, 0.f, 0.f};
    acc[1] = (f32x4){0.f, 0.f, 0.f, 0.f};

    const size_t a0 = (size_t)(bm + wr + fr) * 32 + quad * 8;
    const size_t b0 = (size_t)(wc + fr) * 32 + quad * 8;
    const size_t b1 = b0 + 16 * 32;
    const size_t astep = (size_t)ROWS * 32;
    const size_t bstep = (size_t)64 * 32;

    const u16* pah = Ah;
    const u16* pal = Al;
    const u16* pb  = B;
#pragma unroll 4
    for (int k0 = 0; k0 < DINNER; k0 += 32) {
        bf16x8 ah = *(const bf16x8*)(pah + a0);
        bf16x8 al = *(const bf16x8*)(pal + a0);
        bf16x8 bv0 = *(const bf16x8*)(pb + b0);
        bf16x8 bv1 = *(const bf16x8*)(pb + b1);
        acc[0] = __builtin_amdgcn_mfma_f32_16x16x32_bf16(ah, bv0, acc[0], 0, 0, 0);
        acc[0] = __builtin_amdgcn_mfma_f32_16x16x32_bf16(al, bv0, acc[0], 0, 0, 0);
        acc[1] = __builtin_amdgcn_mfma_f32_16x16x32_bf16(ah, bv1, acc[1], 0, 0, 0);
        acc[1] = __builtin_amdgcn_mfma_f32_16x16x32_bf16(al, bv1, acc[1], 0, 0, 0);
        pah += astep; pal += astep; pb += bstep;
    }

    const int r0 = bm + wr + quad * 4;
#pragma unroll
    for (int reg = 0; reg < 4; reg++) {
        const int row = r0 + reg;
#pragma unroll
        for (int j = 0; j < 2; j++) {
            const int col = wc + 16 * j + fr;
            if (col < 48) C[(size_t)row * 48 + col] = acc[j][reg];
        }
    }
}

// ---------------------------------------------------------------------------
// Round-8: W_out GEMM + LayerNorm FUSED (measured-good).
// ---------------------------------------------------------------------------
__global__ __launch_bounds__(256) void gemm_out_ln(
    const u16* __restrict__ Ah, const u16* __restrict__ Al,
    const u16* __restrict__ B,
    const float* __restrict__ g, const float* __restrict__ b2,
    u16* __restrict__ Yh, u16* __restrict__ Yl)
{
    const int tid  = threadIdx.x;
    const int wave = tid >> 6, lane = tid & 63;
    const int bm   = blockIdx.x * 16;
    const int wc   = wave * 64;            // each wave: 64 cols of all 16 rows
    const int fr   = lane & 15, quad = lane >> 4;

    __shared__ float gb[512];              // g[0..255], b[256..511]
    __shared__ float redS[4][16];          // [wave][quad*4+reg] partial sums
    __shared__ float redQ[4][16];
    if (tid < 256) { gb[tid] = g[tid]; gb[256 + tid] = b2[tid]; }

    f32x4 acc[4];
#pragma unroll
    for (int j = 0; j < 4; j++) acc[j] = (f32x4){0.f, 0.f, 0.f, 0.f};

    const size_t a0 = (size_t)(bm + fr) * 32 + quad * 8;
    size_t bofs[4];
#pragma unroll
    for (int j = 0; j < 4; j++)
        bofs[j] = (size_t)(wc + 16 * j + fr) * 32 + quad * 8;
    const size_t astep = (size_t)ROWS * 32;
    const size_t bstep = (size_t)DMODEL * 32;

    const u16* pah = Ah;
    const u16* pal = Al;
    const u16* pb  = B;
#pragma unroll 2
    for (int k0 = 0; k0 < DINNER; k0 += 32) {
        bf16x8 ah = *(const bf16x8*)(pah + a0);
        bf16x8 al = *(const bf16x8*)(pal + a0);
        bf16x8 bv[4];
#pragma unroll
        for (int j = 0; j < 4; j++) bv[j] = *(const bf16x8*)(pb + bofs[j]);
#pragma unroll
        for (int j = 0; j < 4; j++) {
            acc[j] = __builtin_amdgcn_mfma_f32_16x16x32_bf16(ah, bv[j], acc[j], 0, 0, 0);
            acc[j] = __builtin_amdgcn_mfma_f32_16x16x32_bf16(al, bv[j], acc[j], 0, 0, 0);
        }
        pah += astep; pal += astep; pb += bstep;
    }

    // ---- LN reduction ----
    float s[4], q[4];
#pragma unroll
    for (int reg = 0; reg < 4; reg++) {
        float ss = 0.f, qq = 0.f;
#pragma unroll
        for (int j = 0; j < 4; j++) {
            float v = acc[j][reg];
            ss += v;
            qq = fmaf(v, v, qq);
        }
        s[reg] = ss; q[reg] = qq;
    }
#pragma unroll
    for (int o = 1; o < 16; o <<= 1) {
#pragma unroll
        for (int reg = 0; reg < 4; reg++) {
            s[reg] += __shfl_xor(s[reg], o, 64);
            q[reg] += __shfl_xor(q[reg], o, 64);
        }
    }
    __syncthreads();
    if (fr == 0) {
#pragma unroll
        for (int reg = 0; reg < 4; reg++) {
            redS[wave][quad * 4 + reg] = s[reg];
            redQ[wave][quad * 4 + reg] = q[reg];
        }
    }
    __syncthreads();

#pragma unroll
    for (int reg = 0; reg < 4; reg++) {
        const int rl = quad * 4 + reg;
        const int row = bm + rl;
        float S = (redS[0][rl] + redS[1][rl]) + (redS[2][rl] + redS[3][rl]);
        float Q = (redQ[0][rl] + redQ[1][rl]) + (redQ[2][rl] + redQ[3][rl]);
        float mean = S * (1.f / 256.f);
        float var  = Q * (1.f / 256.f) - mean * mean;
        float inv  = rsqrtf(var + 1e-5f);
#pragma unroll
        for (int j = 0; j < 4; j++) {
            const int col = wc + 16 * j + fr;
            float o = (acc[j][reg] - mean) * inv * gb[col] + gb[256 + col];
            u16 h, l;
            cvt_hl(o, h, l);
            size_t sw = swa(ROWS, row, col);
            Yh[sw] = h;
            Yl[sw] = l;
        }
    }
}

// causal depthwise conv (k=4) + bias + silu -> swizzled bf16 pair xc.
// Round-7: 4 rows/thread sliding window (measured-good).
__global__ __launch_bounds__(256) void conv_silu_k(
    const float* __restrict__ xz, const float* __restrict__ cw,
    const float* __restrict__ cb, u16* __restrict__ xch, u16* __restrict__ xcl)
{
    int idx = blockIdx.x * 256 + threadIdx.x;   // < ROWS*512/4
    int d  = idx & (DINNER - 1);
    int rb = idx >> 9;                          // 0..2047
    int row0 = rb * 4;
    int tb = row0 & (SEQ_LEN - 1);
    float4 w = *(const float4*)(cw + d * 4);
    const float bbv = cb[d];
    const float* p = xz + (size_t)row0 * 1024 + d;
    float xm3 = 0.f, xm2 = 0.f, xm1 = 0.f;
    if (tb >= 4) { xm3 = p[-3 * 1024]; xm2 = p[-2 * 1024]; xm1 = p[-1 * 1024]; }
    float x0 = p[0], x1 = p[1024], x2 = p[2 * 1024], x3 = p[3 * 1024];
    float o[4];
    float a;
    a = bbv; a = fmaf(xm3, w.x, a); a = fmaf(xm2, w.y, a); a = fmaf(xm1, w.z, a); a = fmaf(x0, w.w, a); o[0] = a;
    a = bbv; a = fmaf(xm2, w.x, a); a = fmaf(xm1, w.y, a); a = fmaf(x0, w.z, a);  a = fmaf(x1, w.w, a); o[1] = a;
    a = bbv; a = fmaf(xm1, w.x, a); a = fmaf(x0, w.y, a);  a = fmaf(x1, w.z, a);  a = fmaf(x2, w.w, a); o[2] = a;
    a = bbv; a = fmaf(x0, w.x, a);  a = fmaf(x1, w.y, a);  a = fmaf(x2, w.z, a);  a = fmaf(x3, w.w, a); o[3] = a;
    size_t sw = swa(ROWS, row0, d);
#pragma unroll
    for (int i = 0; i < 4; i++) {
        u16 h, l;
        cvt_hl(siluf(o[i]), h, l);
        xch[sw + i * 32] = h;   // consecutive rows: +32 u16 within same kgroup
        xcl[sw + i * 32] = l;
    }
}

// ---------------------------------------------------------------------------
// Chunked selective scan — r9 structure with two fixes (round-10):
//  (a) Conflict-free pre-pass: thread (wave w, lane l) handles row ch=l,
//      t=w+rr*8 -> LDS write dst = t*512 + l*8: consecutive lanes write a
//      contiguous 2KB span per wave (r9's (r&15)*512 mapping put 16 lanes
//      on bank 0 -> 2.42M conflicts/dispatch). Values bitwise identical.
//  (b) Phase A/C unroll 2 -> 4: r9 counters (VALU 30%, all L3-resident,
//      latency-bound) show only 2 load-batches in flight; 4-deep doubles
//      MLP. NOT r4's failure mode (full unroll-16 + live dtc array);
//      spill signature to watch: VGPR->128 + WRITE_SIZE blowup.
// ---------------------------------------------------------------------------
__global__ __launch_bounds__(512, 4) void scan_k(
    u16* __restrict__ xch,           // swizzled pair hi; in: xc, out: y
    u16* __restrict__ xcl,           // pair lo
    const float* __restrict__ xdbl,  // [ROWS][48]  (dtr at +0, B at +16, C at +32)
    const float* __restrict__ xz,    // [ROWS][1024]  z at +512
    const float* __restrict__ A_log, // [512][16]
    const float* __restrict__ Dp,    // [512]
    const float* __restrict__ Wdt,   // [512][16]
    const float* __restrict__ bdt)   // [512]
{
    const int tid = threadIdx.x;
    const int dl  = tid & (BD - 1);      // 0..7
    const int ch  = tid >> 3;            // 0..63
    const int b   = blockIdx.x & 7;      // batch -> XCD partition
    const int dg  = blockIdx.x >> 3;     // 0..63
    const int d   = dg * BD + dl;
    const int d0  = dg * BD;             // block's first d

    __shared__ float ldsS[NCHUNK * BD * 16];   // 32 KB (xcv, then S, then h0, then xcv)
    __shared__ float ldsD[CHUNK * 512];        // 32 KB dt stash [t][tid]
    __shared__ float ldsT[NCHUNK * BD];        // 2 KB  per-(chunk,d) sdt

    // per-thread dt weights (one-time 64B, shared across the wave's 8 d's)
    float wv[16];
#pragma unroll
    for (int i = 0; i < 16; i += 4) *(float4*)&wv[i] = *(const float4*)(Wdt + d * 16 + i);
    const float bb = bdt[d];

    bool pow_ok = true;
#pragma unroll
    for (int n = 0; n < 16; n++) {
        float An = -expf(A_log[d * 16 + n]);
        pow_ok = pow_ok && (fabsf(An + (float)(n + 1)) <= 1e-3f * (float)(n + 1));
    }
    const int t0 = b * SEQ_LEN + ch * CHUNK;
    const int base = (ch * BD + dl) * 16;    // == tid*16
    const size_t xcb = ((size_t)(d >> 5) * ROWS) * 32 + (d & 31);  // + row*32

    // base global index for the block's 8-d xc segment of row r (in batch b):
    // gi(r) = ((d0>>5)*ROWS + b*SEQ_LEN + r)*32 + (d0&31)   [u16 units, 16B aligned]
    const size_t gseg = ((size_t)(d0 >> 5) * ROWS + (size_t)b * SEQ_LEN) * 32 + (d0 & 31);

    // conflict-free pre-pass mapping: wave wv_, lane ln_ -> row ch=ln_, t=wv_+rr*8
    const int wv_ = tid >> 6;            // 0..7
    const int ln_ = tid & 63;            // 0..63

    // ---- Pre-pass 1: cooperative xc -> LDS (f32), conflict-free writes ----
#pragma unroll
    for (int rr = 0; rr < 2; ++rr) {
        const int t_ = wv_ + rr * 8;             // 0..15
        const int r  = ln_ * 16 + t_;            // row in batch
        const size_t gi = gseg + (size_t)r * 32;
        u16x8 hv = *(const u16x8*)(xch + gi);
        u16x8 lv = *(const u16x8*)(xcl + gi);
        float* dst = ldsS + t_ * 512 + ln_ * 8;  // contiguous per wave
#pragma unroll
        for (int i = 0; i < 8; i++) dst[i] = pair_f(hv[i], lv[i]);
    }
    __syncthreads();

    // ---- Phase A ----
    float S[16];
#pragma unroll
    for (int n = 0; n < 16; n++) S[n] = 0.f;
    float sdt = 0.f;
#pragma unroll 4
    for (int t = 0; t < CHUNK; ++t) {
        const size_t row = (size_t)(t0 + t);
        const float* xr = xdbl + row * 48;
        float qv[16], Bv[16];
#pragma unroll
        for (int i = 0; i < 16; i += 4) *(float4*)&qv[i] = *(const float4*)(xr + i);
#pragma unroll
        for (int i = 0; i < 16; i += 4) *(float4*)&Bv[i] = *(const float4*)(xr + 16 + i);
        float xcv = ldsS[t * 512 + tid];
        // tree-reduced dot (depth ~5 instead of 16-deep serial fmaf chain)
        float s8[8];
#pragma unroll
        for (int i = 0; i < 8; i++) s8[i] = fmaf(qv[i], wv[i], qv[i + 8] * wv[i + 8]);
        float s4_0 = s8[0] + s8[4], s4_1 = s8[1] + s8[5];
        float s4_2 = s8[2] + s8[6], s4_3 = s8[3] + s8[7];
        float dot = bb + ((s4_0 + s4_2) + (s4_1 + s4_3));
        float dtv = softplus_fast(dot);
        ldsD[t * 512 + tid] = dtv;           // stash for phase C
        sdt += dtv;
        float u = dtv * xcv;
        float p[16];
        if (pow_ok) {
            float e1 = fexpf(-dtv);
            p[0] = e1;
#pragma unroll
            for (int n = 1; n < 8; n++) p[n] = p[n - 1] * e1;
            float e8 = p[7];
#pragma unroll
            for (int n = 8; n < 16; n++) p[n] = p[n - 8] * e8;
        } else {
#pragma unroll
            for (int n = 0; n < 16; n++)
                p[n] = exp2f(dtv * (-expf(A_log[d * 16 + n])) * 1.44269504f);
        }
#pragma unroll
        for (int n = 0; n < 16; n++) S[n] = fmaf(p[n], S[n], u * Bv[n]);
    }
    __syncthreads();   // all xcv reads done before S overwrites ldsS
#pragma unroll
    for (int i = 0; i < 16; i += 4) *(float4*)&ldsS[base + i] = *(float4*)&S[i];
    ldsT[tid] = sdt;
    __syncthreads();

    // ---- Phase B: serial prefix over 64 chunks; Pv recomputed from sdt ----
    if (tid < BD * 16) {
        const int dd = tid >> 4;             // 0..7
        const int nn = tid & 15;
        const float An = -fexpf(A_log[(dg * BD + dd) * 16 + nn]);
        float h0 = 0.f;
#pragma unroll 4
        for (int c = 0; c < NCHUNK; ++c) {
            const int idx = (c * BD + dd) * 16 + nn;
            float sdtc = ldsT[c * BD + dd];
            float Sv = ldsS[idx];
            float Pv = fexpf(sdtc * An);
            ldsS[idx] = h0;
            h0 = fmaf(Pv, h0, Sv);
        }
    }
    __syncthreads();

    // ---- h readback, then Pre-pass 2: refill ldsS with xcv for phase C ----
    float h[16];
#pragma unroll
    for (int i = 0; i < 16; i += 4) *(float4*)&h[i] = *(float4*)&ldsS[base + i];
    __syncthreads();   // h reads done before xcv overwrites ldsS
#pragma unroll
    for (int rr = 0; rr < 2; ++rr) {
        const int t_ = wv_ + rr * 8;
        const int r  = ln_ * 16 + t_;
        const size_t gi = gseg + (size_t)r * 32;
        u16x8 hv = *(const u16x8*)(xch + gi);
        u16x8 lv = *(const u16x8*)(xcl + gi);
        float* dst = ldsS + t_ * 512 + ln_ * 8;
#pragma unroll
        for (int i = 0; i < 8; i++) dst[i] = pair_f(hv[i], lv[i]);
    }
    __syncthreads();

    // ---- Phase C ----
    const float Dd = Dp[d];
#pragma unroll 4
    for (int t = 0; t < CHUNK; ++t) {
        const size_t row = (size_t)(t0 + t);
        const float* xr = xdbl + row * 48;
        float Bv[16], Cv[16];
#pragma unroll
        for (int i = 0; i < 16; i += 4) *(float4*)&Bv[i] = *(const float4*)(xr + 16 + i);
#pragma unroll
        for (int i = 0; i < 16; i += 4) *(float4*)&Cv[i] = *(const float4*)(xr + 32 + i);
        float xcv = ldsS[t * 512 + tid];
        float zv  = xz[row * 1024 + 512 + d];
        float dtv = ldsD[t * 512 + tid];     // LDS carry from phase A
        float u = dtv * xcv;
        float p[16];
        if (pow_ok) {
            float e1 = fexpf(-dtv);
            p[0] = e1;
#pragma unroll
            for (int n = 1; n < 8; n++) p[n] = p[n - 1] * e1;
            float e8 = p[7];
#pragma unroll
            for (int n = 8; n < 16; n++) p[n] = p[n - 8] * e8;
        } else {
#pragma unroll
            for (int n = 0; n < 16; n++)
                p[n] = exp2f(dtv * (-expf(A_log[d * 16 + n])) * 1.44269504f);
        }
        float y = 0.f;
#pragma unroll
        for (int n = 0; n < 16; n++) {
            h[n] = fmaf(p[n], h[n], u * Bv[n]);
            y = fmaf(h[n], Cv[n], y);
        }
        y = fmaf(Dd, xcv, y);
        y *= silu_fast(zv);
        u16 yh, yl;
        cvt_hl(y, yh, yl);
        xch[xcb + row * 32] = yh;
        xcl[xcb + row * 32] = yl;
    }
}

// final stage 1: per (b, t-chunk of 16) partial dot with Wf -> part[512]
__global__ __launch_bounds__(256) void final1_k(
    const u16* __restrict__ Hh, const u16* __restrict__ Hl,
    const float* __restrict__ Wf, float* __restrict__ part)
{
    const int b   = blockIdx.x >> 6;     // 0..7
    const int ckt = blockIdx.x & 63;     // 0..63
    const int c   = threadIdx.x;
    const size_t cb = ((size_t)(c >> 5) * ROWS) * 32 + (c & 31);
    const int tbase = b * SEQ_LEN + ckt * 16;
    float s = 0.f;
#pragma unroll 4
    for (int t = 0; t < 16; t++) {
        size_t sw = cb + (size_t)(tbase + t) * 32;
        s += pair_f(Hh[sw], Hl[sw]);
    }
    float v = s * Wf[c];
    int lane = c & 63;
#pragma unroll
    for (int o = 1; o < 64; o <<= 1) v += __shfl_xor(v, o, 64);
    __shared__ float red[4];
    if (lane == 0) red[c >> 6] = v;
    __syncthreads();
    if (c == 0) part[blockIdx.x] = red[0] + red[1] + red[2] + red[3];
}

// final stage 2: combine 64 partials per batch
__global__ __launch_bounds__(512) void final2_k(
    const float* __restrict__ part, const float* __restrict__ bf,
    float* __restrict__ out)
{
    int tid = threadIdx.x;            // 512
    int b = tid >> 6, i = tid & 63;
    float v = part[b * 64 + i];
#pragma unroll
    for (int o = 1; o < 64; o <<= 1) v += __shfl_xor(v, o, 64);
    if (i == 0) out[b] = v * (1.f / 1024.f) + bf[0];
}

extern "C" void kernel_launch(void* const* d_in, const int* in_sizes, int n_in,
                              void* d_out, int out_size, void* d_ws, size_t ws_size,
                              hipStream_t stream)
{
    const float* x      = (const float*)d_in[0];
    const float* Wp     = (const float*)d_in[1];
    const float* bp     = (const float*)d_in[2];
    const float* W_in   = (const float*)d_in[3];
    const float* conv_w = (const float*)d_in[4];
    const float* conv_b = (const float*)d_in[5];
    const float* W_x    = (const float*)d_in[6];
    const float* W_dt   = (const float*)d_in[7];
    const float* b_dt   = (const float*)d_in[8];
    const float* A_log  = (const float*)d_in[9];
    const float* Dp     = (const float*)d_in[10];
    const float* W_out  = (const float*)d_in[11];
    const float* ln_g   = (const float*)d_in[12];
    const float* ln_b   = (const float*)d_in[13];
    const float* Wf     = (const float*)d_in[14];
    const float* bf     = (const float*)d_in[15];

    // ---- workspace layout ----
    char* w = (char*)d_ws;
    float* bufXZ = (float*)w;            w += (size_t)ROWS * 1024 * 4;  // 33.55 MB
    float* bufXD = (float*)w;            w += (size_t)ROWS * 48 * 4;    // 1.57 MB
    u16* xch  = (u16*)w;                 w += (size_t)ROWS * 512 * 2;
    u16* xcl  = (u16*)w;                 w += (size_t)ROWS * 512 * 2;
    u16* hh   = (u16*)w;                 w += (size_t)ROWS * 256 * 2;
    u16* hl   = (u16*)w;                 w += (size_t)ROWS * 256 * 2;
    u16* xih  = (u16*)w;                 w += (size_t)ROWS * 64 * 2;
    u16* xil  = (u16*)w;                 w += (size_t)ROWS * 64 * 2;
    u16* Wpb  = (u16*)w;                 w += (size_t)256 * 64 * 2;
    u16* Wib  = (u16*)w;                 w += (size_t)4 * 1024 * 256 * 2;
    u16* Wxb  = (u16*)w;                 w += (size_t)4 * 64 * 512 * 2;   // padded
    u16* Wob  = (u16*)w;                 w += (size_t)4 * 256 * 512 * 2;
    float* part = (float*)w;             w += 512 * 4;

    dim3 blk(256);

    // one-time conversions (swizzled)
    cvt_x_swz<<<dim3(ROWS * 64 / 256), blk, 0, stream>>>(x, xih, xil);
    cvt_w_swz<<<dim3((CWT + 255) / 256), blk, 0, stream>>>(
        Wp, W_in, W_x, W_out, Wpb, Wib, Wxb, Wob);

    // h = x @ Wp^T + bp  (M=8192, N=Npad=256, K=64) -> swizzled pair
    gemm_sw<1><<<dim3(4, 128), blk, 0, stream>>>(xih, xil, Wpb, bp,
                                                 nullptr, hh, hl,
                                                 ROWS, DMODEL, DMODEL, 64, 0);

    for (int l = 0; l < 4; ++l) {
        const u16* Wil = Wib + (size_t)l * 1024 * 256;
        const u16* Wxl = Wxb + (size_t)l * 64 * 512;
        const u16* Wol = Wob + (size_t)l * 256 * 512;
        const float* cw  = conv_w + (size_t)l * DINNER * 4;
        const float* cb  = conv_b + (size_t)l * DINNER;
        const float* Wdt = W_dt   + (size_t)l * DINNER * DTRANK;
        const float* bdt = b_dt   + (size_t)l * DINNER;
        const float* Al  = A_log  + (size_t)l * DINNER * DSTATE;
        const float* Dl  = Dp     + (size_t)l * DINNER;
        const float* lg  = ln_g   + (size_t)l * DMODEL;
        const float* lb  = ln_b   + (size_t)l * DMODEL;

        // xz = h @ W_in^T  (N=Npad=1024, K=256) -> fp32, wide 64x128 tiles
        gemm_sw128<<<dim3(8, 128), blk, 0, stream>>>(hh, hl, Wil, bufXZ,
                                                     ROWS, 1024, DMODEL, 1024);
        // conv + silu -> xc swizzled pairs (4 rows/thread)
        conv_silu_k<<<dim3(ROWS * DINNER / 4 / 256), blk, 0, stream>>>(
            bufXZ, cw, cb, xch, xcl);
        // x_dbl = xc @ W_x^T  (N=48, K=512) -> fp32 row-major, 256 blocks
        gemm_xdbl<<<dim3(ROWS / 32), blk, 0, stream>>>(xch, xcl, Wxl, bufXD);
        // chunked selective scan (conflict-free staging + 4-deep pipeline)
        scan_k<<<dim3(512), dim3(512), 0, stream>>>(xch, xcl, bufXD, bufXZ,
                                                    Al, Dl, Wdt, bdt);
        // out = LN(y @ W_out^T) -> h swizzled pairs, fused (no bufO)
        gemm_out_ln<<<dim3(ROWS / 16), blk, 0, stream>>>(xch, xcl, Wol,
                                                         lg, lb, hh, hl);
    }

    final1_k<<<dim3(512), blk, 0, stream>>>(hh, hl, Wf, part);
    final2_k<<<dim3(1), dim3(512), 0, stream>>>(part, bf, (float*)d_out);

    (void)in_sizes; (void)n_in; (void)out_size; (void)ws_size;
}

// Round 12
// 534.896 us; speedup vs baseline: 1.4528x; 1.4528x over previous
//
#include <hip/hip_runtime.h>
#include <hip/hip_bf16.h>
#include <math.h>

#define SEQ_LEN 1024
#define BATCH_N 8
#define DMODEL 256
#define DINNER 512
#define DSTATE 16
#define DTRANK 16
#define ROWS (BATCH_N * SEQ_LEN)   // 8192
#define NCHUNK 64
#define CHUNK (SEQ_LEN / NCHUNK)   // 16
#define BD 8                       // d-channels per block (scan)

typedef unsigned short u16;
typedef u16 u16x8 __attribute__((ext_vector_type(8)));
typedef short bf16x8 __attribute__((ext_vector_type(8)));
typedef float f32x4 __attribute__((ext_vector_type(4)));

__device__ __forceinline__ float siluf(float x) { return x / (1.f + expf(-x)); }
__device__ __forceinline__ float softplusf(float x) {
    return fmaxf(x, 0.f) + log1pf(expf(-fabsf(x)));
}
// fast-math variants (scan-only; ~2ulp) — round-5 measured-good (-7.4us).
__device__ __forceinline__ float fexpf(float x) { return __expf(x); }
__device__ __forceinline__ float softplus_fast(float x) {
    return fmaxf(x, 0.f) + __logf(1.f + __expf(-fabsf(x)));
}
__device__ __forceinline__ float silu_fast(float x) {
    return x * __builtin_amdgcn_rcpf(1.f + __expf(-x));
}
__device__ __forceinline__ u16 bf16_rne(float x) {
    unsigned u = __builtin_bit_cast(unsigned, x);
    return (u16)((u + 0x7FFFu + ((u >> 16) & 1u)) >> 16);
}
__device__ __forceinline__ void cvt_hl(float x, u16& h, u16& l) {
    unsigned u = __builtin_bit_cast(unsigned, x);
    unsigned hb = (u + 0x7FFFu + ((u >> 16) & 1u)) >> 16;
    h = (u16)hb;
    float hf = __builtin_bit_cast(float, hb << 16);
    l = bf16_rne(x - hf);
}
__device__ __forceinline__ float pair_f(u16 h, u16 l) {
    return __builtin_bit_cast(float, (unsigned)h << 16) +
           __builtin_bit_cast(float, (unsigned)l << 16);
}
// fragment-swizzled activation address: tensor [R rows][Kc cols] stored as
// [Kc/32][R][32]; elem (row,c) at ((c>>5)*R + row)*32 + (c&31)
__device__ __forceinline__ size_t swa(int R, int row, int c) {
    return ((size_t)(c >> 5) * R + row) * 32 + (c & 31);
}

// x fp32 [8192][64] -> swizzled bf16 hi/lo pairs
__global__ __launch_bounds__(256) void cvt_x_swz(
    const float* __restrict__ x, u16* __restrict__ dh, u16* __restrict__ dl)
{
    int i = blockIdx.x * 256 + threadIdx.x;   // < ROWS*64
    int row = i >> 6, c = i & 63;
    u16 h, l;
    cvt_hl(x[i], h, l);
    size_t sw = swa(ROWS, row, c);
    dh[sw] = h;
    dl[sw] = l;
}

// all 4 weight tensors -> fragment-swizzled single bf16 ([k/32][Npad][32])
// segments: Wp(256x64), W_in 4x(1024x256), W_x 4x(48->64 x 512), W_out 4x(256x512)
#define CWT (16384 + 4 * 262144 + 4 * 32768 + 4 * 131072)   // 1720320
__global__ __launch_bounds__(256) void cvt_w_swz(
    const float* __restrict__ Wp, const float* __restrict__ W_in,
    const float* __restrict__ W_x, const float* __restrict__ W_out,
    u16* __restrict__ Wpb, u16* __restrict__ Wib,
    u16* __restrict__ Wxb, u16* __restrict__ Wob)
{
    long i = (long)blockIdx.x * 256 + threadIdx.x;
    if (i >= CWT) return;
    if (i < 16384) {                       // Wp: N=256 K=64
        int n = (int)(i >> 6), k = (int)(i & 63);
        Wpb[((k >> 5) * 256 + n) * 32 + (k & 31)] = bf16_rne(Wp[n * 64 + k]);
        return;
    }
    i -= 16384;
    if (i < 4 * 262144) {                  // W_in: N=1024 K=256
        int l = (int)(i >> 18), r = (int)(i & 262143);
        int n = r >> 8, k = r & 255;
        Wib[l * 262144 + ((k >> 5) * 1024 + n) * 32 + (k & 31)] =
            bf16_rne(W_in[l * 262144 + n * 256 + k]);
        return;
    }
    i -= 4 * 262144;
    if (i < 4 * 32768) {                   // W_x: N=48 (pad 64) K=512
        int l = (int)(i >> 15), r = (int)(i & 32767);
        int n = r >> 9, k = r & 511;
        float v = (n < 48) ? W_x[l * 48 * 512 + n * 512 + k] : 0.f;
        Wxb[l * 32768 + ((k >> 5) * 64 + n) * 32 + (k & 31)] = bf16_rne(v);
        return;
    }
    i -= 4 * 32768;
    {                                      // W_out: N=256 K=512
        int l = (int)(i >> 17), r = (int)(i & 131071);
        int n = r >> 9, k = r & 511;
        Wob[l * 131072 + ((k >> 5) * 256 + n) * 32 + (k & 31)] =
            bf16_rne(W_out[l * 131072 + n * 512 + k]);
    }
}

// ---------------------------------------------------------------------------
// LDS-free MFMA GEMM on fragment-swizzled operands (round-11 measured-good).
// ---------------------------------------------------------------------------
template<int EPI>
__global__ __launch_bounds__(256) void gemm_sw(
    const u16* __restrict__ Ah, const u16* __restrict__ Al,
    const u16* __restrict__ B,
    const float* __restrict__ bias, float* __restrict__ C,
    u16* __restrict__ Ch, u16* __restrict__ Cl,
    int M, int N, int Npad, int K, int ldc)
{
    const int tid  = threadIdx.x;
    const int wave = tid >> 6, lane = tid & 63;
    const int bm   = blockIdx.y * 64, bn = blockIdx.x * 64;
    const int wm   = (wave >> 1) * 32, wn = (wave & 1) * 32;
    const int fr   = lane & 15, quad = lane >> 4;

    f32x4 acc[2][2];
#pragma unroll
    for (int i = 0; i < 2; i++)
#pragma unroll
        for (int j = 0; j < 2; j++) acc[i][j] = (f32x4){0.f, 0.f, 0.f, 0.f};

    const size_t a0 = (size_t)(bm + wm + fr) * 32 + quad * 8;
    const size_t a1 = a0 + 16 * 32;
    const size_t b0 = (size_t)(bn + wn + fr) * 32 + quad * 8;
    const size_t b1 = b0 + 16 * 32;
    const size_t astep = (size_t)M * 32;
    const size_t bstep = (size_t)Npad * 32;

    const u16* pah = Ah;
    const u16* pal = Al;
    const u16* pb  = B;
#pragma unroll 2
    for (int k0 = 0; k0 < K; k0 += 32) {
        bf16x8 ah0 = *(const bf16x8*)(pah + a0);
        bf16x8 ah1 = *(const bf16x8*)(pah + a1);
        bf16x8 al0 = *(const bf16x8*)(pal + a0);
        bf16x8 al1 = *(const bf16x8*)(pal + a1);
        bf16x8 bv0 = *(const bf16x8*)(pb + b0);
        bf16x8 bv1 = *(const bf16x8*)(pb + b1);
        acc[0][0] = __builtin_amdgcn_mfma_f32_16x16x32_bf16(ah0, bv0, acc[0][0], 0, 0, 0);
        acc[0][0] = __builtin_amdgcn_mfma_f32_16x16x32_bf16(al0, bv0, acc[0][0], 0, 0, 0);
        acc[0][1] = __builtin_amdgcn_mfma_f32_16x16x32_bf16(ah0, bv1, acc[0][1], 0, 0, 0);
        acc[0][1] = __builtin_amdgcn_mfma_f32_16x16x32_bf16(al0, bv1, acc[0][1], 0, 0, 0);
        acc[1][0] = __builtin_amdgcn_mfma_f32_16x16x32_bf16(ah1, bv0, acc[1][0], 0, 0, 0);
        acc[1][0] = __builtin_amdgcn_mfma_f32_16x16x32_bf16(al1, bv0, acc[1][0], 0, 0, 0);
        acc[1][1] = __builtin_amdgcn_mfma_f32_16x16x32_bf16(ah1, bv1, acc[1][1], 0, 0, 0);
        acc[1][1] = __builtin_amdgcn_mfma_f32_16x16x32_bf16(al1, bv1, acc[1][1], 0, 0, 0);
        pah += astep; pal += astep; pb += bstep;
    }

    // C/D layout (m89-verified): row = quad*4 + reg, col = fr within 16x16 frag
#pragma unroll
    for (int i = 0; i < 2; i++) {
        const int r0 = bm + wm + 16 * i + quad * 4;
#pragma unroll
        for (int reg = 0; reg < 4; reg++) {
            const int row = r0 + reg;
#pragma unroll
            for (int j = 0; j < 2; j++) {
                const int col = bn + wn + 16 * j + fr;
                if (col < N) {
                    float v = acc[i][j][reg];
                    if (bias) v += bias[col];
                    if (EPI == 0) {
                        C[(size_t)row * ldc + col] = v;
                    } else {
                        u16 h, l;
                        cvt_hl(v, h, l);
                        size_t sw = swa(M, row, col);
                        Ch[sw] = h;
                        Cl[sw] = l;
                    }
                }
            }
        }
    }
}

// ---------------------------------------------------------------------------
// Wide variant: 64x128 block (4 waves 2x2, each 32x64 = 2x4 frags).
// ---------------------------------------------------------------------------
__global__ __launch_bounds__(256) void gemm_sw128(
    const u16* __restrict__ Ah, const u16* __restrict__ Al,
    const u16* __restrict__ B, float* __restrict__ C,
    int M, int Npad, int K, int ldc)
{
    const int tid  = threadIdx.x;
    const int wave = tid >> 6, lane = tid & 63;
    const int bm   = blockIdx.y * 64, bn = blockIdx.x * 128;
    const int wm   = (wave >> 1) * 32, wn = (wave & 1) * 64;
    const int fr   = lane & 15, quad = lane >> 4;

    f32x4 acc[2][4];
#pragma unroll
    for (int i = 0; i < 2; i++)
#pragma unroll
        for (int j = 0; j < 4; j++) acc[i][j] = (f32x4){0.f, 0.f, 0.f, 0.f};

    const size_t a0 = (size_t)(bm + wm + fr) * 32 + quad * 8;
    const size_t a1 = a0 + 16 * 32;
    size_t bofs[4];
#pragma unroll
    for (int j = 0; j < 4; j++)
        bofs[j] = (size_t)(bn + wn + 16 * j + fr) * 32 + quad * 8;
    const size_t astep = (size_t)M * 32;
    const size_t bstep = (size_t)Npad * 32;

    const u16* pah = Ah;
    const u16* pal = Al;
    const u16* pb  = B;
    for (int k0 = 0; k0 < K; k0 += 32) {
        bf16x8 ah0 = *(const bf16x8*)(pah + a0);
        bf16x8 ah1 = *(const bf16x8*)(pah + a1);
        bf16x8 al0 = *(const bf16x8*)(pal + a0);
        bf16x8 al1 = *(const bf16x8*)(pal + a1);
        bf16x8 bv[4];
#pragma unroll
        for (int j = 0; j < 4; j++) bv[j] = *(const bf16x8*)(pb + bofs[j]);
#pragma unroll
        for (int j = 0; j < 4; j++) {
            acc[0][j] = __builtin_amdgcn_mfma_f32_16x16x32_bf16(ah0, bv[j], acc[0][j], 0, 0, 0);
            acc[0][j] = __builtin_amdgcn_mfma_f32_16x16x32_bf16(al0, bv[j], acc[0][j], 0, 0, 0);
            acc[1][j] = __builtin_amdgcn_mfma_f32_16x16x32_bf16(ah1, bv[j], acc[1][j], 0, 0, 0);
            acc[1][j] = __builtin_amdgcn_mfma_f32_16x16x32_bf16(al1, bv[j], acc[1][j], 0, 0, 0);
        }
        pah += astep; pal += astep; pb += bstep;
    }

#pragma unroll
    for (int i = 0; i < 2; i++) {
        const int r0 = bm + wm + 16 * i + quad * 4;
#pragma unroll
        for (int reg = 0; reg < 4; reg++) {
            float* crow = C + (size_t)(r0 + reg) * ldc;
#pragma unroll
            for (int j = 0; j < 4; j++)
                crow[bn + wn + 16 * j + fr] = acc[i][j][reg];
        }
    }
}

// ---------------------------------------------------------------------------
// xdbl GEMM specialization (round-7 measured-good): M=8192, N=48 (Npad=64),
// K=512; 32rx64c blocks, grid 256.
// ---------------------------------------------------------------------------
__global__ __launch_bounds__(256) void gemm_xdbl(
    const u16* __restrict__ Ah, const u16* __restrict__ Al,
    const u16* __restrict__ B, float* __restrict__ C)
{
    const int tid  = threadIdx.x;
    const int wave = tid >> 6, lane = tid & 63;
    const int bm   = blockIdx.x * 32;
    const int wr   = (wave >> 1) * 16;    // row-half within the 32-row tile
    const int wc   = (wave & 1) * 32;     // col-half within the 64-col tile
    const int fr   = lane & 15, quad = lane >> 4;

    f32x4 acc[2];
    acc[0] = (f32x4){0.f, 0.f, 0.f, 0.f};
    acc[1] = (f32x4){0.f, 0.f, 0.f, 0.f};

    const size_t a0 = (size_t)(bm + wr + fr) * 32 + quad * 8;
    const size_t b0 = (size_t)(wc + fr) * 32 + quad * 8;
    const size_t b1 = b0 + 16 * 32;
    const size_t astep = (size_t)ROWS * 32;
    const size_t bstep = (size_t)64 * 32;

    const u16* pah = Ah;
    const u16* pal = Al;
    const u16* pb  = B;
#pragma unroll 4
    for (int k0 = 0; k0 < DINNER; k0 += 32) {
        bf16x8 ah = *(const bf16x8*)(pah + a0);
        bf16x8 al = *(const bf16x8*)(pal + a0);
        bf16x8 bv0 = *(const bf16x8*)(pb + b0);
        bf16x8 bv1 = *(const bf16x8*)(pb + b1);
        acc[0] = __builtin_amdgcn_mfma_f32_16x16x32_bf16(ah, bv0, acc[0], 0, 0, 0);
        acc[0] = __builtin_amdgcn_mfma_f32_16x16x32_bf16(al, bv0, acc[0], 0, 0, 0);
        acc[1] = __builtin_amdgcn_mfma_f32_16x16x32_bf16(ah, bv1, acc[1], 0, 0, 0);
        acc[1] = __builtin_amdgcn_mfma_f32_16x16x32_bf16(al, bv1, acc[1], 0, 0, 0);
        pah += astep; pal += astep; pb += bstep;
    }

    const int r0 = bm + wr + quad * 4;
#pragma unroll
    for (int reg = 0; reg < 4; reg++) {
        const int row = r0 + reg;
#pragma unroll
        for (int j = 0; j < 2; j++) {
            const int col = wc + 16 * j + fr;
            if (col < 48) C[(size_t)row * 48 + col] = acc[j][reg];
        }
    }
}

// ---------------------------------------------------------------------------
// Round-8: W_out GEMM + LayerNorm FUSED (measured-good).
// ---------------------------------------------------------------------------
__global__ __launch_bounds__(256) void gemm_out_ln(
    const u16* __restrict__ Ah, const u16* __restrict__ Al,
    const u16* __restrict__ B,
    const float* __restrict__ g, const float* __restrict__ b2,
    u16* __restrict__ Yh, u16* __restrict__ Yl)
{
    const int tid  = threadIdx.x;
    const int wave = tid >> 6, lane = tid & 63;
    const int bm   = blockIdx.x * 16;
    const int wc   = wave * 64;            // each wave: 64 cols of all 16 rows
    const int fr   = lane & 15, quad = lane >> 4;

    __shared__ float gb[512];              // g[0..255], b[256..511]
    __shared__ float redS[4][16];          // [wave][quad*4+reg] partial sums
    __shared__ float redQ[4][16];
    if (tid < 256) { gb[tid] = g[tid]; gb[256 + tid] = b2[tid]; }

    f32x4 acc[4];
#pragma unroll
    for (int j = 0; j < 4; j++) acc[j] = (f32x4){0.f, 0.f, 0.f, 0.f};

    const size_t a0 = (size_t)(bm + fr) * 32 + quad * 8;
    size_t bofs[4];
#pragma unroll
    for (int j = 0; j < 4; j++)
        bofs[j] = (size_t)(wc + 16 * j + fr) * 32 + quad * 8;
    const size_t astep = (size_t)ROWS * 32;
    const size_t bstep = (size_t)DMODEL * 32;

    const u16* pah = Ah;
    const u16* pal = Al;
    const u16* pb  = B;
#pragma unroll 2
    for (int k0 = 0; k0 < DINNER; k0 += 32) {
        bf16x8 ah = *(const bf16x8*)(pah + a0);
        bf16x8 al = *(const bf16x8*)(pal + a0);
        bf16x8 bv[4];
#pragma unroll
        for (int j = 0; j < 4; j++) bv[j] = *(const bf16x8*)(pb + bofs[j]);
#pragma unroll
        for (int j = 0; j < 4; j++) {
            acc[j] = __builtin_amdgcn_mfma_f32_16x16x32_bf16(ah, bv[j], acc[j], 0, 0, 0);
            acc[j] = __builtin_amdgcn_mfma_f32_16x16x32_bf16(al, bv[j], acc[j], 0, 0, 0);
        }
        pah += astep; pal += astep; pb += bstep;
    }

    // ---- LN reduction ----
    float s[4], q[4];
#pragma unroll
    for (int reg = 0; reg < 4; reg++) {
        float ss = 0.f, qq = 0.f;
#pragma unroll
        for (int j = 0; j < 4; j++) {
            float v = acc[j][reg];
            ss += v;
            qq = fmaf(v, v, qq);
        }
        s[reg] = ss; q[reg] = qq;
    }
#pragma unroll
    for (int o = 1; o < 16; o <<= 1) {
#pragma unroll
        for (int reg = 0; reg < 4; reg++) {
            s[reg] += __shfl_xor(s[reg], o, 64);
            q[reg] += __shfl_xor(q[reg], o, 64);
        }
    }
    __syncthreads();
    if (fr == 0) {
#pragma unroll
        for (int reg = 0; reg < 4; reg++) {
            redS[wave][quad * 4 + reg] = s[reg];
            redQ[wave][quad * 4 + reg] = q[reg];
        }
    }
    __syncthreads();

#pragma unroll
    for (int reg = 0; reg < 4; reg++) {
        const int rl = quad * 4 + reg;
        const int row = bm + rl;
        float S = (redS[0][rl] + redS[1][rl]) + (redS[2][rl] + redS[3][rl]);
        float Q = (redQ[0][rl] + redQ[1][rl]) + (redQ[2][rl] + redQ[3][rl]);
        float mean = S * (1.f / 256.f);
        float var  = Q * (1.f / 256.f) - mean * mean;
        float inv  = rsqrtf(var + 1e-5f);
#pragma unroll
        for (int j = 0; j < 4; j++) {
            const int col = wc + 16 * j + fr;
            float o = (acc[j][reg] - mean) * inv * gb[col] + gb[256 + col];
            u16 h, l;
            cvt_hl(o, h, l);
            size_t sw = swa(ROWS, row, col);
            Yh[sw] = h;
            Yl[sw] = l;
        }
    }
}

// causal depthwise conv (k=4) + bias + silu -> swizzled bf16 pair xc.
// Round-7: 4 rows/thread sliding window (measured-good).
__global__ __launch_bounds__(256) void conv_silu_k(
    const float* __restrict__ xz, const float* __restrict__ cw,
    const float* __restrict__ cb, u16* __restrict__ xch, u16* __restrict__ xcl)
{
    int idx = blockIdx.x * 256 + threadIdx.x;   // < ROWS*512/4
    int d  = idx & (DINNER - 1);
    int rb = idx >> 9;                          // 0..2047
    int row0 = rb * 4;
    int tb = row0 & (SEQ_LEN - 1);
    float4 w = *(const float4*)(cw + d * 4);
    const float bbv = cb[d];
    const float* p = xz + (size_t)row0 * 1024 + d;
    float xm3 = 0.f, xm2 = 0.f, xm1 = 0.f;
    if (tb >= 4) { xm3 = p[-3 * 1024]; xm2 = p[-2 * 1024]; xm1 = p[-1 * 1024]; }
    float x0 = p[0], x1 = p[1024], x2 = p[2 * 1024], x3 = p[3 * 1024];
    float o[4];
    float a;
    a = bbv; a = fmaf(xm3, w.x, a); a = fmaf(xm2, w.y, a); a = fmaf(xm1, w.z, a); a = fmaf(x0, w.w, a); o[0] = a;
    a = bbv; a = fmaf(xm2, w.x, a); a = fmaf(xm1, w.y, a); a = fmaf(x0, w.z, a);  a = fmaf(x1, w.w, a); o[1] = a;
    a = bbv; a = fmaf(xm1, w.x, a); a = fmaf(x0, w.y, a);  a = fmaf(x1, w.z, a);  a = fmaf(x2, w.w, a); o[2] = a;
    a = bbv; a = fmaf(x0, w.x, a);  a = fmaf(x1, w.y, a);  a = fmaf(x2, w.z, a);  a = fmaf(x3, w.w, a); o[3] = a;
    size_t sw = swa(ROWS, row0, d);
#pragma unroll
    for (int i = 0; i < 4; i++) {
        u16 h, l;
        cvt_hl(siluf(o[i]), h, l);
        xch[sw + i * 32] = h;   // consecutive rows: +32 u16 within same kgroup
        xcl[sw + i * 32] = l;
    }
}

// ---------------------------------------------------------------------------
// Chunked selective scan — round-11: r9 structure + conflict-free pre-pass
// (r10's fix (a), verified: bank conflicts 2.42M -> 852K) with phases A/C
// back at #pragma unroll 2. r10's unroll-4 reproduced r4's scratch-spill
// signature EXACTLY (VGPR reads 64 but FETCH/WRITE blow up 6-10x, VALU
// collapses): the allocator holds its 64-VGPR choice and spills rather than
// grow. TWICE-CONFIRMED CONSTRAINT: phases A/C must stay at unroll 2.
// ---------------------------------------------------------------------------
__global__ __launch_bounds__(512, 4) void scan_k(
    u16* __restrict__ xch,           // swizzled pair hi; in: xc, out: y
    u16* __restrict__ xcl,           // pair lo
    const float* __restrict__ xdbl,  // [ROWS][48]  (dtr at +0, B at +16, C at +32)
    const float* __restrict__ xz,    // [ROWS][1024]  z at +512
    const float* __restrict__ A_log, // [512][16]
    const float* __restrict__ Dp,    // [512]
    const float* __restrict__ Wdt,   // [512][16]
    const float* __restrict__ bdt)   // [512]
{
    const int tid = threadIdx.x;
    const int dl  = tid & (BD - 1);      // 0..7
    const int ch  = tid >> 3;            // 0..63
    const int b   = blockIdx.x & 7;      // batch -> XCD partition
    const int dg  = blockIdx.x >> 3;     // 0..63
    const int d   = dg * BD + dl;
    const int d0  = dg * BD;             // block's first d

    __shared__ float ldsS[NCHUNK * BD * 16];   // 32 KB (xcv, then S, then h0, then xcv)
    __shared__ float ldsD[CHUNK * 512];        // 32 KB dt stash [t][tid]
    __shared__ float ldsT[NCHUNK * BD];        // 2 KB  per-(chunk,d) sdt

    // per-thread dt weights (one-time 64B, shared across the wave's 8 d's)
    float wv[16];
#pragma unroll
    for (int i = 0; i < 16; i += 4) *(float4*)&wv[i] = *(const float4*)(Wdt + d * 16 + i);
    const float bb = bdt[d];

    bool pow_ok = true;
#pragma unroll
    for (int n = 0; n < 16; n++) {
        float An = -expf(A_log[d * 16 + n]);
        pow_ok = pow_ok && (fabsf(An + (float)(n + 1)) <= 1e-3f * (float)(n + 1));
    }
    const int t0 = b * SEQ_LEN + ch * CHUNK;
    const int base = (ch * BD + dl) * 16;    // == tid*16
    const size_t xcb = ((size_t)(d >> 5) * ROWS) * 32 + (d & 31);  // + row*32

    // base global index for the block's 8-d xc segment of row r (in batch b):
    // gi(r) = ((d0>>5)*ROWS + b*SEQ_LEN + r)*32 + (d0&31)   [u16 units, 16B aligned]
    const size_t gseg = ((size_t)(d0 >> 5) * ROWS + (size_t)b * SEQ_LEN) * 32 + (d0 & 31);

    // conflict-free pre-pass mapping: wave wv_, lane ln_ -> row ch=ln_, t=wv_+rr*8
    const int wv_ = tid >> 6;            // 0..7
    const int ln_ = tid & 63;            // 0..63

    // ---- Pre-pass 1: cooperative xc -> LDS (f32), conflict-free writes ----
#pragma unroll
    for (int rr = 0; rr < 2; ++rr) {
        const int t_ = wv_ + rr * 8;             // 0..15
        const int r  = ln_ * 16 + t_;            // row in batch
        const size_t gi = gseg + (size_t)r * 32;
        u16x8 hv = *(const u16x8*)(xch + gi);
        u16x8 lv = *(const u16x8*)(xcl + gi);
        float* dst = ldsS + t_ * 512 + ln_ * 8;  // contiguous per wave
#pragma unroll
        for (int i = 0; i < 8; i++) dst[i] = pair_f(hv[i], lv[i]);
    }
    __syncthreads();

    // ---- Phase A ----
    float S[16];
#pragma unroll
    for (int n = 0; n < 16; n++) S[n] = 0.f;
    float sdt = 0.f;
#pragma unroll 2
    for (int t = 0; t < CHUNK; ++t) {
        const size_t row = (size_t)(t0 + t);
        const float* xr = xdbl + row * 48;
        float qv[16], Bv[16];
#pragma unroll
        for (int i = 0; i < 16; i += 4) *(float4*)&qv[i] = *(const float4*)(xr + i);
#pragma unroll
        for (int i = 0; i < 16; i += 4) *(float4*)&Bv[i] = *(const float4*)(xr + 16 + i);
        float xcv = ldsS[t * 512 + tid];
        // tree-reduced dot (depth ~5 instead of 16-deep serial fmaf chain)
        float s8[8];
#pragma unroll
        for (int i = 0; i < 8; i++) s8[i] = fmaf(qv[i], wv[i], qv[i + 8] * wv[i + 8]);
        float s4_0 = s8[0] + s8[4], s4_1 = s8[1] + s8[5];
        float s4_2 = s8[2] + s8[6], s4_3 = s8[3] + s8[7];
        float dot = bb + ((s4_0 + s4_2) + (s4_1 + s4_3));
        float dtv = softplus_fast(dot);
        ldsD[t * 512 + tid] = dtv;           // stash for phase C
        sdt += dtv;
        float u = dtv * xcv;
        float p[16];
        if (pow_ok) {
            float e1 = fexpf(-dtv);
            p[0] = e1;
#pragma unroll
            for (int n = 1; n < 8; n++) p[n] = p[n - 1] * e1;
            float e8 = p[7];
#pragma unroll
            for (int n = 8; n < 16; n++) p[n] = p[n - 8] * e8;
        } else {
#pragma unroll
            for (int n = 0; n < 16; n++)
                p[n] = exp2f(dtv * (-expf(A_log[d * 16 + n])) * 1.44269504f);
        }
#pragma unroll
        for (int n = 0; n < 16; n++) S[n] = fmaf(p[n], S[n], u * Bv[n]);
    }
    __syncthreads();   // all xcv reads done before S overwrites ldsS
#pragma unroll
    for (int i = 0; i < 16; i += 4) *(float4*)&ldsS[base + i] = *(float4*)&S[i];
    ldsT[tid] = sdt;
    __syncthreads();

    // ---- Phase B: serial prefix over 64 chunks; Pv recomputed from sdt ----
    if (tid < BD * 16) {
        const int dd = tid >> 4;             // 0..7
        const int nn = tid & 15;
        const float An = -fexpf(A_log[(dg * BD + dd) * 16 + nn]);
        float h0 = 0.f;
#pragma unroll 4
        for (int c = 0; c < NCHUNK; ++c) {
            const int idx = (c * BD + dd) * 16 + nn;
            float sdtc = ldsT[c * BD + dd];
            float Sv = ldsS[idx];
            float Pv = fexpf(sdtc * An);
            ldsS[idx] = h0;
            h0 = fmaf(Pv, h0, Sv);
        }
    }
    __syncthreads();

    // ---- h readback, then Pre-pass 2: refill ldsS with xcv for phase C ----
    float h[16];
#pragma unroll
    for (int i = 0; i < 16; i += 4) *(float4*)&h[i] = *(float4*)&ldsS[base + i];
    __syncthreads();   // h reads done before xcv overwrites ldsS
#pragma unroll
    for (int rr = 0; rr < 2; ++rr) {
        const int t_ = wv_ + rr * 8;
        const int r  = ln_ * 16 + t_;
        const size_t gi = gseg + (size_t)r * 32;
        u16x8 hv = *(const u16x8*)(xch + gi);
        u16x8 lv = *(const u16x8*)(xcl + gi);
        float* dst = ldsS + t_ * 512 + ln_ * 8;
#pragma unroll
        for (int i = 0; i < 8; i++) dst[i] = pair_f(hv[i], lv[i]);
    }
    __syncthreads();

    // ---- Phase C ----
    const float Dd = Dp[d];
#pragma unroll 2
    for (int t = 0; t < CHUNK; ++t) {
        const size_t row = (size_t)(t0 + t);
        const float* xr = xdbl + row * 48;
        float Bv[16], Cv[16];
#pragma unroll
        for (int i = 0; i < 16; i += 4) *(float4*)&Bv[i] = *(const float4*)(xr + 16 + i);
#pragma unroll
        for (int i = 0; i < 16; i += 4) *(float4*)&Cv[i] = *(const float4*)(xr + 32 + i);
        float xcv = ldsS[t * 512 + tid];
        float zv  = xz[row * 1024 + 512 + d];
        float dtv = ldsD[t * 512 + tid];     // LDS carry from phase A
        float u = dtv * xcv;
        float p[16];
        if (pow_ok) {
            float e1 = fexpf(-dtv);
            p[0] = e1;
#pragma unroll
            for (int n = 1; n < 8; n++) p[n] = p[n - 1] * e1;
            float e8 = p[7];
#pragma unroll
            for (int n = 8; n < 16; n++) p[n] = p[n - 8] * e8;
        } else {
#pragma unroll
            for (int n = 0; n < 16; n++)
                p[n] = exp2f(dtv * (-expf(A_log[d * 16 + n])) * 1.44269504f);
        }
        float y = 0.f;
#pragma unroll
        for (int n = 0; n < 16; n++) {
            h[n] = fmaf(p[n], h[n], u * Bv[n]);
            y = fmaf(h[n], Cv[n], y);
        }
        y = fmaf(Dd, xcv, y);
        y *= silu_fast(zv);
        u16 yh, yl;
        cvt_hl(y, yh, yl);
        xch[xcb + row * 32] = yh;
        xcl[xcb + row * 32] = yl;
    }
}

// final stage 1: per (b, t-chunk of 16) partial dot with Wf -> part[512]
__global__ __launch_bounds__(256) void final1_k(
    const u16* __restrict__ Hh, const u16* __restrict__ Hl,
    const float* __restrict__ Wf, float* __restrict__ part)
{
    const int b   = blockIdx.x >> 6;     // 0..7
    const int ckt = blockIdx.x & 63;     // 0..63
    const int c   = threadIdx.x;
    const size_t cb = ((size_t)(c >> 5) * ROWS) * 32 + (c & 31);
    const int tbase = b * SEQ_LEN + ckt * 16;
    float s = 0.f;
#pragma unroll 4
    for (int t = 0; t < 16; t++) {
        size_t sw = cb + (size_t)(tbase + t) * 32;
        s += pair_f(Hh[sw], Hl[sw]);
    }
    float v = s * Wf[c];
    int lane = c & 63;
#pragma unroll
    for (int o = 1; o < 64; o <<= 1) v += __shfl_xor(v, o, 64);
    __shared__ float red[4];
    if (lane == 0) red[c >> 6] = v;
    __syncthreads();
    if (c == 0) part[blockIdx.x] = red[0] + red[1] + red[2] + red[3];
}

// final stage 2: combine 64 partials per batch
__global__ __launch_bounds__(512) void final2_k(
    const float* __restrict__ part, const float* __restrict__ bf,
    float* __restrict__ out)
{
    int tid = threadIdx.x;            // 512
    int b = tid >> 6, i = tid & 63;
    float v = part[b * 64 + i];
#pragma unroll
    for (int o = 1; o < 64; o <<= 1) v += __shfl_xor(v, o, 64);
    if (i == 0) out[b] = v * (1.f / 1024.f) + bf[0];
}

extern "C" void kernel_launch(void* const* d_in, const int* in_sizes, int n_in,
                              void* d_out, int out_size, void* d_ws, size_t ws_size,
                              hipStream_t stream)
{
    const float* x      = (const float*)d_in[0];
    const float* Wp     = (const float*)d_in[1];
    const float* bp     = (const float*)d_in[2];
    const float* W_in   = (const float*)d_in[3];
    const float* conv_w = (const float*)d_in[4];
    const float* conv_b = (const float*)d_in[5];
    const float* W_x    = (const float*)d_in[6];
    const float* W_dt   = (const float*)d_in[7];
    const float* b_dt   = (const float*)d_in[8];
    const float* A_log  = (const float*)d_in[9];
    const float* Dp     = (const float*)d_in[10];
    const float* W_out  = (const float*)d_in[11];
    const float* ln_g   = (const float*)d_in[12];
    const float* ln_b   = (const float*)d_in[13];
    const float* Wf     = (const float*)d_in[14];
    const float* bf     = (const float*)d_in[15];

    // ---- workspace layout ----
    char* w = (char*)d_ws;
    float* bufXZ = (float*)w;            w += (size_t)ROWS * 1024 * 4;  // 33.55 MB
    float* bufXD = (float*)w;            w += (size_t)ROWS * 48 * 4;    // 1.57 MB
    u16* xch  = (u16*)w;                 w += (size_t)ROWS * 512 * 2;
    u16* xcl  = (u16*)w;                 w += (size_t)ROWS * 512 * 2;
    u16* hh   = (u16*)w;                 w += (size_t)ROWS * 256 * 2;
    u16* hl   = (u16*)w;                 w += (size_t)ROWS * 256 * 2;
    u16* xih  = (u16*)w;                 w += (size_t)ROWS * 64 * 2;
    u16* xil  = (u16*)w;                 w += (size_t)ROWS * 64 * 2;
    u16* Wpb  = (u16*)w;                 w += (size_t)256 * 64 * 2;
    u16* Wib  = (u16*)w;                 w += (size_t)4 * 1024 * 256 * 2;
    u16* Wxb  = (u16*)w;                 w += (size_t)4 * 64 * 512 * 2;   // padded
    u16* Wob  = (u16*)w;                 w += (size_t)4 * 256 * 512 * 2;
    float* part = (float*)w;             w += 512 * 4;

    dim3 blk(256);

    // one-time conversions (swizzled)
    cvt_x_swz<<<dim3(ROWS * 64 / 256), blk, 0, stream>>>(x, xih, xil);
    cvt_w_swz<<<dim3((CWT + 255) / 256), blk, 0, stream>>>(
        Wp, W_in, W_x, W_out, Wpb, Wib, Wxb, Wob);

    // h = x @ Wp^T + bp  (M=8192, N=Npad=256, K=64) -> swizzled pair
    gemm_sw<1><<<dim3(4, 128), blk, 0, stream>>>(xih, xil, Wpb, bp,
                                                 nullptr, hh, hl,
                                                 ROWS, DMODEL, DMODEL, 64, 0);

    for (int l = 0; l < 4; ++l) {
        const u16* Wil = Wib + (size_t)l * 1024 * 256;
        const u16* Wxl = Wxb + (size_t)l * 64 * 512;
        const u16* Wol = Wob + (size_t)l * 256 * 512;
        const float* cw  = conv_w + (size_t)l * DINNER * 4;
        const float* cb  = conv_b + (size_t)l * DINNER;
        const float* Wdt = W_dt   + (size_t)l * DINNER * DTRANK;
        const float* bdt = b_dt   + (size_t)l * DINNER;
        const float* Al  = A_log  + (size_t)l * DINNER * DSTATE;
        const float* Dl  = Dp     + (size_t)l * DINNER;
        const float* lg  = ln_g   + (size_t)l * DMODEL;
        const float* lb  = ln_b   + (size_t)l * DMODEL;

        // xz = h @ W_in^T  (N=Npad=1024, K=256) -> fp32, wide 64x128 tiles
        gemm_sw128<<<dim3(8, 128), blk, 0, stream>>>(hh, hl, Wil, bufXZ,
                                                     ROWS, 1024, DMODEL, 1024);
        // conv + silu -> xc swizzled pairs (4 rows/thread)
        conv_silu_k<<<dim3(ROWS * DINNER / 4 / 256), blk, 0, stream>>>(
            bufXZ, cw, cb, xch, xcl);
        // x_dbl = xc @ W_x^T  (N=48, K=512) -> fp32 row-major, 256 blocks
        gemm_xdbl<<<dim3(ROWS / 32), blk, 0, stream>>>(xch, xcl, Wxl, bufXD);
        // chunked selective scan (conflict-free staging, unroll 2)
        scan_k<<<dim3(512), dim3(512), 0, stream>>>(xch, xcl, bufXD, bufXZ,
                                                    Al, Dl, Wdt, bdt);
        // out = LN(y @ W_out^T) -> h swizzled pairs, fused (no bufO)
        gemm_out_ln<<<dim3(ROWS / 16), blk, 0, stream>>>(xch, xcl, Wol,
                                                         lg, lb, hh, hl);
    }

    final1_k<<<dim3(512), blk, 0, stream>>>(hh, hl, Wf, part);
    final2_k<<<dim3(1), dim3(512), 0, stream>>>(part, bf, (float*)d_out);

    (void)in_sizes; (void)n_in; (void)out_size; (void)ws_size;
}

// Round 13
// 527.676 us; speedup vs baseline: 1.4726x; 1.0137x over previous
//
#include <hip/hip_runtime.h>
#include <hip/hip_bf16.h>
#include <math.h>

#define SEQ_LEN 1024
#define BATCH_N 8
#define DMODEL 256
#define DINNER 512
#define DSTATE 16
#define DTRANK 16
#define ROWS (BATCH_N * SEQ_LEN)   // 8192
#define NCHUNK 64
#define CHUNK (SEQ_LEN / NCHUNK)   // 16
#define BD 8                       // d-channels per block (scan)

typedef unsigned short u16;
typedef u16 u16x8 __attribute__((ext_vector_type(8)));
typedef short bf16x8 __attribute__((ext_vector_type(8)));
typedef float f32x4 __attribute__((ext_vector_type(4)));

__device__ __forceinline__ float siluf(float x) { return x / (1.f + expf(-x)); }
__device__ __forceinline__ float softplusf(float x) {
    return fmaxf(x, 0.f) + log1pf(expf(-fabsf(x)));
}
// fast-math variants (scan-only; ~2ulp) — round-5 measured-good (-7.4us).
__device__ __forceinline__ float fexpf(float x) { return __expf(x); }
__device__ __forceinline__ float softplus_fast(float x) {
    return fmaxf(x, 0.f) + __logf(1.f + __expf(-fabsf(x)));
}
__device__ __forceinline__ float silu_fast(float x) {
    return x * __builtin_amdgcn_rcpf(1.f + __expf(-x));
}
__device__ __forceinline__ u16 bf16_rne(float x) {
    unsigned u = __builtin_bit_cast(unsigned, x);
    return (u16)((u + 0x7FFFu + ((u >> 16) & 1u)) >> 16);
}
__device__ __forceinline__ void cvt_hl(float x, u16& h, u16& l) {
    unsigned u = __builtin_bit_cast(unsigned, x);
    unsigned hb = (u + 0x7FFFu + ((u >> 16) & 1u)) >> 16;
    h = (u16)hb;
    float hf = __builtin_bit_cast(float, hb << 16);
    l = bf16_rne(x - hf);
}
__device__ __forceinline__ float pair_f(u16 h, u16 l) {
    return __builtin_bit_cast(float, (unsigned)h << 16) +
           __builtin_bit_cast(float, (unsigned)l << 16);
}
// fragment-swizzled activation address: tensor [R rows][Kc cols] stored as
// [Kc/32][R][32]; elem (row,c) at ((c>>5)*R + row)*32 + (c&31)
__device__ __forceinline__ size_t swa(int R, int row, int c) {
    return ((size_t)(c >> 5) * R + row) * 32 + (c & 31);
}

// x fp32 [8192][64] -> swizzled bf16 hi/lo pairs
__global__ __launch_bounds__(256) void cvt_x_swz(
    const float* __restrict__ x, u16* __restrict__ dh, u16* __restrict__ dl)
{
    int i = blockIdx.x * 256 + threadIdx.x;   // < ROWS*64
    int row = i >> 6, c = i & 63;
    u16 h, l;
    cvt_hl(x[i], h, l);
    size_t sw = swa(ROWS, row, c);
    dh[sw] = h;
    dl[sw] = l;
}

// all 4 weight tensors -> fragment-swizzled single bf16 ([k/32][Npad][32])
// segments: Wp(256x64), W_in 4x(1024x256), W_x 4x(48->64 x 512), W_out 4x(256x512)
#define CWT (16384 + 4 * 262144 + 4 * 32768 + 4 * 131072)   // 1720320
__global__ __launch_bounds__(256) void cvt_w_swz(
    const float* __restrict__ Wp, const float* __restrict__ W_in,
    const float* __restrict__ W_x, const float* __restrict__ W_out,
    u16* __restrict__ Wpb, u16* __restrict__ Wib,
    u16* __restrict__ Wxb, u16* __restrict__ Wob)
{
    long i = (long)blockIdx.x * 256 + threadIdx.x;
    if (i >= CWT) return;
    if (i < 16384) {                       // Wp: N=256 K=64
        int n = (int)(i >> 6), k = (int)(i & 63);
        Wpb[((k >> 5) * 256 + n) * 32 + (k & 31)] = bf16_rne(Wp[n * 64 + k]);
        return;
    }
    i -= 16384;
    if (i < 4 * 262144) {                  // W_in: N=1024 K=256
        int l = (int)(i >> 18), r = (int)(i & 262143);
        int n = r >> 8, k = r & 255;
        Wib[l * 262144 + ((k >> 5) * 1024 + n) * 32 + (k & 31)] =
            bf16_rne(W_in[l * 262144 + n * 256 + k]);
        return;
    }
    i -= 4 * 262144;
    if (i < 4 * 32768) {                   // W_x: N=48 (pad 64) K=512
        int l = (int)(i >> 15), r = (int)(i & 32767);
        int n = r >> 9, k = r & 511;
        float v = (n < 48) ? W_x[l * 48 * 512 + n * 512 + k] : 0.f;
        Wxb[l * 32768 + ((k >> 5) * 64 + n) * 32 + (k & 31)] = bf16_rne(v);
        return;
    }
    i -= 4 * 32768;
    {                                      // W_out: N=256 K=512
        int l = (int)(i >> 17), r = (int)(i & 131071);
        int n = r >> 9, k = r & 511;
        Wob[l * 131072 + ((k >> 5) * 256 + n) * 32 + (k & 31)] =
            bf16_rne(W_out[l * 131072 + n * 512 + k]);
    }
}

// ---------------------------------------------------------------------------
// LDS-free MFMA GEMM on fragment-swizzled operands (round-11 measured-good).
// ---------------------------------------------------------------------------
template<int EPI>
__global__ __launch_bounds__(256) void gemm_sw(
    const u16* __restrict__ Ah, const u16* __restrict__ Al,
    const u16* __restrict__ B,
    const float* __restrict__ bias, float* __restrict__ C,
    u16* __restrict__ Ch, u16* __restrict__ Cl,
    int M, int N, int Npad, int K, int ldc)
{
    const int tid  = threadIdx.x;
    const int wave = tid >> 6, lane = tid & 63;
    const int bm   = blockIdx.y * 64, bn = blockIdx.x * 64;
    const int wm   = (wave >> 1) * 32, wn = (wave & 1) * 32;
    const int fr   = lane & 15, quad = lane >> 4;

    f32x4 acc[2][2];
#pragma unroll
    for (int i = 0; i < 2; i++)
#pragma unroll
        for (int j = 0; j < 2; j++) acc[i][j] = (f32x4){0.f, 0.f, 0.f, 0.f};

    const size_t a0 = (size_t)(bm + wm + fr) * 32 + quad * 8;
    const size_t a1 = a0 + 16 * 32;
    const size_t b0 = (size_t)(bn + wn + fr) * 32 + quad * 8;
    const size_t b1 = b0 + 16 * 32;
    const size_t astep = (size_t)M * 32;
    const size_t bstep = (size_t)Npad * 32;

    const u16* pah = Ah;
    const u16* pal = Al;
    const u16* pb  = B;
#pragma unroll 2
    for (int k0 = 0; k0 < K; k0 += 32) {
        bf16x8 ah0 = *(const bf16x8*)(pah + a0);
        bf16x8 ah1 = *(const bf16x8*)(pah + a1);
        bf16x8 al0 = *(const bf16x8*)(pal + a0);
        bf16x8 al1 = *(const bf16x8*)(pal + a1);
        bf16x8 bv0 = *(const bf16x8*)(pb + b0);
        bf16x8 bv1 = *(const bf16x8*)(pb + b1);
        acc[0][0] = __builtin_amdgcn_mfma_f32_16x16x32_bf16(ah0, bv0, acc[0][0], 0, 0, 0);
        acc[0][0] = __builtin_amdgcn_mfma_f32_16x16x32_bf16(al0, bv0, acc[0][0], 0, 0, 0);
        acc[0][1] = __builtin_amdgcn_mfma_f32_16x16x32_bf16(ah0, bv1, acc[0][1], 0, 0, 0);
        acc[0][1] = __builtin_amdgcn_mfma_f32_16x16x32_bf16(al0, bv1, acc[0][1], 0, 0, 0);
        acc[1][0] = __builtin_amdgcn_mfma_f32_16x16x32_bf16(ah1, bv0, acc[1][0], 0, 0, 0);
        acc[1][0] = __builtin_amdgcn_mfma_f32_16x16x32_bf16(al1, bv0, acc[1][0], 0, 0, 0);
        acc[1][1] = __builtin_amdgcn_mfma_f32_16x16x32_bf16(ah1, bv1, acc[1][1], 0, 0, 0);
        acc[1][1] = __builtin_amdgcn_mfma_f32_16x16x32_bf16(al1, bv1, acc[1][1], 0, 0, 0);
        pah += astep; pal += astep; pb += bstep;
    }

    // C/D layout (m89-verified): row = quad*4 + reg, col = fr within 16x16 frag
#pragma unroll
    for (int i = 0; i < 2; i++) {
        const int r0 = bm + wm + 16 * i + quad * 4;
#pragma unroll
        for (int reg = 0; reg < 4; reg++) {
            const int row = r0 + reg;
#pragma unroll
            for (int j = 0; j < 2; j++) {
                const int col = bn + wn + 16 * j + fr;
                if (col < N) {
                    float v = acc[i][j][reg];
                    if (bias) v += bias[col];
                    if (EPI == 0) {
                        C[(size_t)row * ldc + col] = v;
                    } else {
                        u16 h, l;
                        cvt_hl(v, h, l);
                        size_t sw = swa(M, row, col);
                        Ch[sw] = h;
                        Cl[sw] = l;
                    }
                }
            }
        }
    }
}

// ---------------------------------------------------------------------------
// Wide variant: 64x128 block (4 waves 2x2, each 32x64 = 2x4 frags).
// ---------------------------------------------------------------------------
__global__ __launch_bounds__(256) void gemm_sw128(
    const u16* __restrict__ Ah, const u16* __restrict__ Al,
    const u16* __restrict__ B, float* __restrict__ C,
    int M, int Npad, int K, int ldc)
{
    const int tid  = threadIdx.x;
    const int wave = tid >> 6, lane = tid & 63;
    const int bm   = blockIdx.y * 64, bn = blockIdx.x * 128;
    const int wm   = (wave >> 1) * 32, wn = (wave & 1) * 64;
    const int fr   = lane & 15, quad = lane >> 4;

    f32x4 acc[2][4];
#pragma unroll
    for (int i = 0; i < 2; i++)
#pragma unroll
        for (int j = 0; j < 4; j++) acc[i][j] = (f32x4){0.f, 0.f, 0.f, 0.f};

    const size_t a0 = (size_t)(bm + wm + fr) * 32 + quad * 8;
    const size_t a1 = a0 + 16 * 32;
    size_t bofs[4];
#pragma unroll
    for (int j = 0; j < 4; j++)
        bofs[j] = (size_t)(bn + wn + 16 * j + fr) * 32 + quad * 8;
    const size_t astep = (size_t)M * 32;
    const size_t bstep = (size_t)Npad * 32;

    const u16* pah = Ah;
    const u16* pal = Al;
    const u16* pb  = B;
    for (int k0 = 0; k0 < K; k0 += 32) {
        bf16x8 ah0 = *(const bf16x8*)(pah + a0);
        bf16x8 ah1 = *(const bf16x8*)(pah + a1);
        bf16x8 al0 = *(const bf16x8*)(pal + a0);
        bf16x8 al1 = *(const bf16x8*)(pal + a1);
        bf16x8 bv[4];
#pragma unroll
        for (int j = 0; j < 4; j++) bv[j] = *(const bf16x8*)(pb + bofs[j]);
#pragma unroll
        for (int j = 0; j < 4; j++) {
            acc[0][j] = __builtin_amdgcn_mfma_f32_16x16x32_bf16(ah0, bv[j], acc[0][j], 0, 0, 0);
            acc[0][j] = __builtin_amdgcn_mfma_f32_16x16x32_bf16(al0, bv[j], acc[0][j], 0, 0, 0);
            acc[1][j] = __builtin_amdgcn_mfma_f32_16x16x32_bf16(ah1, bv[j], acc[1][j], 0, 0, 0);
            acc[1][j] = __builtin_amdgcn_mfma_f32_16x16x32_bf16(al1, bv[j], acc[1][j], 0, 0, 0);
        }
        pah += astep; pal += astep; pb += bstep;
    }

#pragma unroll
    for (int i = 0; i < 2; i++) {
        const int r0 = bm + wm + 16 * i + quad * 4;
#pragma unroll
        for (int reg = 0; reg < 4; reg++) {
            float* crow = C + (size_t)(r0 + reg) * ldc;
#pragma unroll
            for (int j = 0; j < 4; j++)
                crow[bn + wn + 16 * j + fr] = acc[i][j][reg];
        }
    }
}

// ---------------------------------------------------------------------------
// xdbl GEMM specialization (round-7 measured-good): M=8192, N=48 (Npad=64),
// K=512; 32rx64c blocks, grid 256.
// ---------------------------------------------------------------------------
__global__ __launch_bounds__(256) void gemm_xdbl(
    const u16* __restrict__ Ah, const u16* __restrict__ Al,
    const u16* __restrict__ B, float* __restrict__ C)
{
    const int tid  = threadIdx.x;
    const int wave = tid >> 6, lane = tid & 63;
    const int bm   = blockIdx.x * 32;
    const int wr   = (wave >> 1) * 16;    // row-half within the 32-row tile
    const int wc   = (wave & 1) * 32;     // col-half within the 64-col tile
    const int fr   = lane & 15, quad = lane >> 4;

    f32x4 acc[2];
    acc[0] = (f32x4){0.f, 0.f, 0.f, 0.f};
    acc[1] = (f32x4){0.f, 0.f, 0.f, 0.f};

    const size_t a0 = (size_t)(bm + wr + fr) * 32 + quad * 8;
    const size_t b0 = (size_t)(wc + fr) * 32 + quad * 8;
    const size_t b1 = b0 + 16 * 32;
    const size_t astep = (size_t)ROWS * 32;
    const size_t bstep = (size_t)64 * 32;

    const u16* pah = Ah;
    const u16* pal = Al;
    const u16* pb  = B;
#pragma unroll 4
    for (int k0 = 0; k0 < DINNER; k0 += 32) {
        bf16x8 ah = *(const bf16x8*)(pah + a0);
        bf16x8 al = *(const bf16x8*)(pal + a0);
        bf16x8 bv0 = *(const bf16x8*)(pb + b0);
        bf16x8 bv1 = *(const bf16x8*)(pb + b1);
        acc[0] = __builtin_amdgcn_mfma_f32_16x16x32_bf16(ah, bv0, acc[0], 0, 0, 0);
        acc[0] = __builtin_amdgcn_mfma_f32_16x16x32_bf16(al, bv0, acc[0], 0, 0, 0);
        acc[1] = __builtin_amdgcn_mfma_f32_16x16x32_bf16(ah, bv1, acc[1], 0, 0, 0);
        acc[1] = __builtin_amdgcn_mfma_f32_16x16x32_bf16(al, bv1, acc[1], 0, 0, 0);
        pah += astep; pal += astep; pb += bstep;
    }

    const int r0 = bm + wr + quad * 4;
#pragma unroll
    for (int reg = 0; reg < 4; reg++) {
        const int row = r0 + reg;
#pragma unroll
        for (int j = 0; j < 2; j++) {
            const int col = wc + 16 * j + fr;
            if (col < 48) C[(size_t)row * 48 + col] = acc[j][reg];
        }
    }
}

// ---------------------------------------------------------------------------
// Round-8: W_out GEMM + LayerNorm FUSED (measured-good).
// ---------------------------------------------------------------------------
__global__ __launch_bounds__(256) void gemm_out_ln(
    const u16* __restrict__ Ah, const u16* __restrict__ Al,
    const u16* __restrict__ B,
    const float* __restrict__ g, const float* __restrict__ b2,
    u16* __restrict__ Yh, u16* __restrict__ Yl)
{
    const int tid  = threadIdx.x;
    const int wave = tid >> 6, lane = tid & 63;
    const int bm   = blockIdx.x * 16;
    const int wc   = wave * 64;            // each wave: 64 cols of all 16 rows
    const int fr   = lane & 15, quad = lane >> 4;

    __shared__ float gb[512];              // g[0..255], b[256..511]
    __shared__ float redS[4][16];          // [wave][quad*4+reg] partial sums
    __shared__ float redQ[4][16];
    if (tid < 256) { gb[tid] = g[tid]; gb[256 + tid] = b2[tid]; }

    f32x4 acc[4];
#pragma unroll
    for (int j = 0; j < 4; j++) acc[j] = (f32x4){0.f, 0.f, 0.f, 0.f};

    const size_t a0 = (size_t)(bm + fr) * 32 + quad * 8;
    size_t bofs[4];
#pragma unroll
    for (int j = 0; j < 4; j++)
        bofs[j] = (size_t)(wc + 16 * j + fr) * 32 + quad * 8;
    const size_t astep = (size_t)ROWS * 32;
    const size_t bstep = (size_t)DMODEL * 32;

    const u16* pah = Ah;
    const u16* pal = Al;
    const u16* pb  = B;
#pragma unroll 2
    for (int k0 = 0; k0 < DINNER; k0 += 32) {
        bf16x8 ah = *(const bf16x8*)(pah + a0);
        bf16x8 al = *(const bf16x8*)(pal + a0);
        bf16x8 bv[4];
#pragma unroll
        for (int j = 0; j < 4; j++) bv[j] = *(const bf16x8*)(pb + bofs[j]);
#pragma unroll
        for (int j = 0; j < 4; j++) {
            acc[j] = __builtin_amdgcn_mfma_f32_16x16x32_bf16(ah, bv[j], acc[j], 0, 0, 0);
            acc[j] = __builtin_amdgcn_mfma_f32_16x16x32_bf16(al, bv[j], acc[j], 0, 0, 0);
        }
        pah += astep; pal += astep; pb += bstep;
    }

    // ---- LN reduction ----
    float s[4], q[4];
#pragma unroll
    for (int reg = 0; reg < 4; reg++) {
        float ss = 0.f, qq = 0.f;
#pragma unroll
        for (int j = 0; j < 4; j++) {
            float v = acc[j][reg];
            ss += v;
            qq = fmaf(v, v, qq);
        }
        s[reg] = ss; q[reg] = qq;
    }
#pragma unroll
    for (int o = 1; o < 16; o <<= 1) {
#pragma unroll
        for (int reg = 0; reg < 4; reg++) {
            s[reg] += __shfl_xor(s[reg], o, 64);
            q[reg] += __shfl_xor(q[reg], o, 64);
        }
    }
    __syncthreads();
    if (fr == 0) {
#pragma unroll
        for (int reg = 0; reg < 4; reg++) {
            redS[wave][quad * 4 + reg] = s[reg];
            redQ[wave][quad * 4 + reg] = q[reg];
        }
    }
    __syncthreads();

#pragma unroll
    for (int reg = 0; reg < 4; reg++) {
        const int rl = quad * 4 + reg;
        const int row = bm + rl;
        float S = (redS[0][rl] + redS[1][rl]) + (redS[2][rl] + redS[3][rl]);
        float Q = (redQ[0][rl] + redQ[1][rl]) + (redQ[2][rl] + redQ[3][rl]);
        float mean = S * (1.f / 256.f);
        float var  = Q * (1.f / 256.f) - mean * mean;
        float inv  = rsqrtf(var + 1e-5f);
#pragma unroll
        for (int j = 0; j < 4; j++) {
            const int col = wc + 16 * j + fr;
            float o = (acc[j][reg] - mean) * inv * gb[col] + gb[256 + col];
            u16 h, l;
            cvt_hl(o, h, l);
            size_t sw = swa(ROWS, row, col);
            Yh[sw] = h;
            Yl[sw] = l;
        }
    }
}

// causal depthwise conv (k=4) + bias + silu -> swizzled bf16 pair xc.
// Round-7: 4 rows/thread sliding window (measured-good).
__global__ __launch_bounds__(256) void conv_silu_k(
    const float* __restrict__ xz, const float* __restrict__ cw,
    const float* __restrict__ cb, u16* __restrict__ xch, u16* __restrict__ xcl)
{
    int idx = blockIdx.x * 256 + threadIdx.x;   // < ROWS*512/4
    int d  = idx & (DINNER - 1);
    int rb = idx >> 9;                          // 0..2047
    int row0 = rb * 4;
    int tb = row0 & (SEQ_LEN - 1);
    float4 w = *(const float4*)(cw + d * 4);
    const float bbv = cb[d];
    const float* p = xz + (size_t)row0 * 1024 + d;
    float xm3 = 0.f, xm2 = 0.f, xm1 = 0.f;
    if (tb >= 4) { xm3 = p[-3 * 1024]; xm2 = p[-2 * 1024]; xm1 = p[-1 * 1024]; }
    float x0 = p[0], x1 = p[1024], x2 = p[2 * 1024], x3 = p[3 * 1024];
    float o[4];
    float a;
    a = bbv; a = fmaf(xm3, w.x, a); a = fmaf(xm2, w.y, a); a = fmaf(xm1, w.z, a); a = fmaf(x0, w.w, a); o[0] = a;
    a = bbv; a = fmaf(xm2, w.x, a); a = fmaf(xm1, w.y, a); a = fmaf(x0, w.z, a);  a = fmaf(x1, w.w, a); o[1] = a;
    a = bbv; a = fmaf(xm1, w.x, a); a = fmaf(x0, w.y, a);  a = fmaf(x1, w.z, a);  a = fmaf(x2, w.w, a); o[2] = a;
    a = bbv; a = fmaf(x0, w.x, a);  a = fmaf(x1, w.y, a);  a = fmaf(x2, w.z, a);  a = fmaf(x3, w.w, a); o[3] = a;
    size_t sw = swa(ROWS, row0, d);
#pragma unroll
    for (int i = 0; i < 4; i++) {
        u16 h, l;
        cvt_hl(siluf(o[i]), h, l);
        xch[sw + i * 32] = h;   // consecutive rows: +32 u16 within same kgroup
        xcl[sw + i * 32] = l;
    }
}

// ---------------------------------------------------------------------------
// Chunked selective scan — round-12: r9's COALESCED pre-pass (r = tid+rr*512,
// 64B lane stride — r11's conflict-free-mapped variant scattered global reads
// at 1KB lane stride and LOST 2.9us despite fixing LDS conflicts) plus an
// XOR swizzle on the LDS stash GROUP index: row r stored at group
// (r>>4) ^ (r&3) instead of (r>>4). Write octet index becomes
// (ch&3)^(t&3) — cycles all 4 octets within each 16-lane run -> 16-way
// conflict drops to 4-way, while reads stay conflict-free (XOR permutes ch
// within a wave's 0..7 range -> still a permutation of a contiguous span)
// and global reads stay r9-coalesced. Values bitwise identical.
// Phases A/C: unroll 2 (TWICE-CONFIRMED: deeper unroll spills to scratch —
// VGPR reads 64 but FETCH/WRITE blow up 6-10x).
// ---------------------------------------------------------------------------
__global__ __launch_bounds__(512, 4) void scan_k(
    u16* __restrict__ xch,           // swizzled pair hi; in: xc, out: y
    u16* __restrict__ xcl,           // pair lo
    const float* __restrict__ xdbl,  // [ROWS][48]  (dtr at +0, B at +16, C at +32)
    const float* __restrict__ xz,    // [ROWS][1024]  z at +512
    const float* __restrict__ A_log, // [512][16]
    const float* __restrict__ Dp,    // [512]
    const float* __restrict__ Wdt,   // [512][16]
    const float* __restrict__ bdt)   // [512]
{
    const int tid = threadIdx.x;
    const int dl  = tid & (BD - 1);      // 0..7
    const int ch  = tid >> 3;            // 0..63
    const int b   = blockIdx.x & 7;      // batch -> XCD partition
    const int dg  = blockIdx.x >> 3;     // 0..63
    const int d   = dg * BD + dl;
    const int d0  = dg * BD;             // block's first d

    __shared__ float ldsS[NCHUNK * BD * 16];   // 32 KB (xcv, then S, then h0, then xcv)
    __shared__ float ldsD[CHUNK * 512];        // 32 KB dt stash [t][tid]
    __shared__ float ldsT[NCHUNK * BD];        // 2 KB  per-(chunk,d) sdt

    // per-thread dt weights (one-time 64B, shared across the wave's 8 d's)
    float wv[16];
#pragma unroll
    for (int i = 0; i < 16; i += 4) *(float4*)&wv[i] = *(const float4*)(Wdt + d * 16 + i);
    const float bb = bdt[d];

    bool pow_ok = true;
#pragma unroll
    for (int n = 0; n < 16; n++) {
        float An = -expf(A_log[d * 16 + n]);
        pow_ok = pow_ok && (fabsf(An + (float)(n + 1)) <= 1e-3f * (float)(n + 1));
    }
    const int t0 = b * SEQ_LEN + ch * CHUNK;
    const int base = (ch * BD + dl) * 16;    // == tid*16
    const size_t xcb = ((size_t)(d >> 5) * ROWS) * 32 + (d & 31);  // + row*32

    // base global index for the block's 8-d xc segment of row r (in batch b):
    // gi(r) = ((d0>>5)*ROWS + b*SEQ_LEN + r)*32 + (d0&31)   [u16 units, 16B aligned]
    const size_t gseg = ((size_t)(d0 >> 5) * ROWS + (size_t)b * SEQ_LEN) * 32 + (d0 & 31);

    // ---- Pre-pass 1: cooperative xc -> LDS (f32); coalesced global reads,
    //      group-XOR-swizzled LDS writes (16-way -> 4-way conflict) ----
#pragma unroll
    for (int rr = 0; rr < 2; ++rr) {
        const int r  = tid + rr * 512;           // 0..1023, lane-consecutive
        const int t_ = r & 15;
        const int c_ = r >> 4;                   // 0..63
        const size_t gi = gseg + (size_t)r * 32;
        u16x8 hv = *(const u16x8*)(xch + gi);
        u16x8 lv = *(const u16x8*)(xcl + gi);
        float* dst = ldsS + t_ * 512 + (c_ ^ (t_ & 3)) * 8;
#pragma unroll
        for (int i = 0; i < 8; i++) dst[i] = pair_f(hv[i], lv[i]);
    }
    __syncthreads();

    // ---- Phase A ----
    float S[16];
#pragma unroll
    for (int n = 0; n < 16; n++) S[n] = 0.f;
    float sdt = 0.f;
#pragma unroll 2
    for (int t = 0; t < CHUNK; ++t) {
        const size_t row = (size_t)(t0 + t);
        const float* xr = xdbl + row * 48;
        float qv[16], Bv[16];
#pragma unroll
        for (int i = 0; i < 16; i += 4) *(float4*)&qv[i] = *(const float4*)(xr + i);
#pragma unroll
        for (int i = 0; i < 16; i += 4) *(float4*)&Bv[i] = *(const float4*)(xr + 16 + i);
        float xcv = ldsS[t * 512 + (ch ^ (t & 3)) * 8 + dl];
        // tree-reduced dot (depth ~5 instead of 16-deep serial fmaf chain)
        float s8[8];
#pragma unroll
        for (int i = 0; i < 8; i++) s8[i] = fmaf(qv[i], wv[i], qv[i + 8] * wv[i + 8]);
        float s4_0 = s8[0] + s8[4], s4_1 = s8[1] + s8[5];
        float s4_2 = s8[2] + s8[6], s4_3 = s8[3] + s8[7];
        float dot = bb + ((s4_0 + s4_2) + (s4_1 + s4_3));
        float dtv = softplus_fast(dot);
        ldsD[t * 512 + tid] = dtv;           // stash for phase C
        sdt += dtv;
        float u = dtv * xcv;
        float p[16];
        if (pow_ok) {
            float e1 = fexpf(-dtv);
            p[0] = e1;
#pragma unroll
            for (int n = 1; n < 8; n++) p[n] = p[n - 1] * e1;
            float e8 = p[7];
#pragma unroll
            for (int n = 8; n < 16; n++) p[n] = p[n - 8] * e8;
        } else {
#pragma unroll
            for (int n = 0; n < 16; n++)
                p[n] = exp2f(dtv * (-expf(A_log[d * 16 + n])) * 1.44269504f);
        }
#pragma unroll
        for (int n = 0; n < 16; n++) S[n] = fmaf(p[n], S[n], u * Bv[n]);
    }
    __syncthreads();   // all xcv reads done before S overwrites ldsS
#pragma unroll
    for (int i = 0; i < 16; i += 4) *(float4*)&ldsS[base + i] = *(float4*)&S[i];
    ldsT[tid] = sdt;
    __syncthreads();

    // ---- Phase B: serial prefix over 64 chunks; Pv recomputed from sdt ----
    if (tid < BD * 16) {
        const int dd = tid >> 4;             // 0..7
        const int nn = tid & 15;
        const float An = -fexpf(A_log[(dg * BD + dd) * 16 + nn]);
        float h0 = 0.f;
#pragma unroll 4
        for (int c = 0; c < NCHUNK; ++c) {
            const int idx = (c * BD + dd) * 16 + nn;
            float sdtc = ldsT[c * BD + dd];
            float Sv = ldsS[idx];
            float Pv = fexpf(sdtc * An);
            ldsS[idx] = h0;
            h0 = fmaf(Pv, h0, Sv);
        }
    }
    __syncthreads();

    // ---- h readback, then Pre-pass 2: refill ldsS with xcv for phase C ----
    float h[16];
#pragma unroll
    for (int i = 0; i < 16; i += 4) *(float4*)&h[i] = *(float4*)&ldsS[base + i];
    __syncthreads();   // h reads done before xcv overwrites ldsS
#pragma unroll
    for (int rr = 0; rr < 2; ++rr) {
        const int r  = tid + rr * 512;
        const int t_ = r & 15;
        const int c_ = r >> 4;
        const size_t gi = gseg + (size_t)r * 32;
        u16x8 hv = *(const u16x8*)(xch + gi);
        u16x8 lv = *(const u16x8*)(xcl + gi);
        float* dst = ldsS + t_ * 512 + (c_ ^ (t_ & 3)) * 8;
#pragma unroll
        for (int i = 0; i < 8; i++) dst[i] = pair_f(hv[i], lv[i]);
    }
    __syncthreads();

    // ---- Phase C ----
    const float Dd = Dp[d];
#pragma unroll 2
    for (int t = 0; t < CHUNK; ++t) {
        const size_t row = (size_t)(t0 + t);
        const float* xr = xdbl + row * 48;
        float Bv[16], Cv[16];
#pragma unroll
        for (int i = 0; i < 16; i += 4) *(float4*)&Bv[i] = *(const float4*)(xr + 16 + i);
#pragma unroll
        for (int i = 0; i < 16; i += 4) *(float4*)&Cv[i] = *(const float4*)(xr + 32 + i);
        float xcv = ldsS[t * 512 + (ch ^ (t & 3)) * 8 + dl];
        float zv  = xz[row * 1024 + 512 + d];
        float dtv = ldsD[t * 512 + tid];     // LDS carry from phase A
        float u = dtv * xcv;
        float p[16];
        if (pow_ok) {
            float e1 = fexpf(-dtv);
            p[0] = e1;
#pragma unroll
            for (int n = 1; n < 8; n++) p[n] = p[n - 1] * e1;
            float e8 = p[7];
#pragma unroll
            for (int n = 8; n < 16; n++) p[n] = p[n - 8] * e8;
        } else {
#pragma unroll
            for (int n = 0; n < 16; n++)
                p[n] = exp2f(dtv * (-expf(A_log[d * 16 + n])) * 1.44269504f);
        }
        float y = 0.f;
#pragma unroll
        for (int n = 0; n < 16; n++) {
            h[n] = fmaf(p[n], h[n], u * Bv[n]);
            y = fmaf(h[n], Cv[n], y);
        }
        y = fmaf(Dd, xcv, y);
        y *= silu_fast(zv);
        u16 yh, yl;
        cvt_hl(y, yh, yl);
        xch[xcb + row * 32] = yh;
        xcl[xcb + row * 32] = yl;
    }
}

// final stage 1: per (b, t-chunk of 16) partial dot with Wf -> part[512]
__global__ __launch_bounds__(256) void final1_k(
    const u16* __restrict__ Hh, const u16* __restrict__ Hl,
    const float* __restrict__ Wf, float* __restrict__ part)
{
    const int b   = blockIdx.x >> 6;     // 0..7
    const int ckt = blockIdx.x & 63;     // 0..63
    const int c   = threadIdx.x;
    const size_t cb = ((size_t)(c >> 5) * ROWS) * 32 + (c & 31);
    const int tbase = b * SEQ_LEN + ckt * 16;
    float s = 0.f;
#pragma unroll 4
    for (int t = 0; t < 16; t++) {
        size_t sw = cb + (size_t)(tbase + t) * 32;
        s += pair_f(Hh[sw], Hl[sw]);
    }
    float v = s * Wf[c];
    int lane = c & 63;
#pragma unroll
    for (int o = 1; o < 64; o <<= 1) v += __shfl_xor(v, o, 64);
    __shared__ float red[4];
    if (lane == 0) red[c >> 6] = v;
    __syncthreads();
    if (c == 0) part[blockIdx.x] = red[0] + red[1] + red[2] + red[3];
}

// final stage 2: combine 64 partials per batch
__global__ __launch_bounds__(512) void final2_k(
    const float* __restrict__ part, const float* __restrict__ bf,
    float* __restrict__ out)
{
    int tid = threadIdx.x;            // 512
    int b = tid >> 6, i = tid & 63;
    float v = part[b * 64 + i];
#pragma unroll
    for (int o = 1; o < 64; o <<= 1) v += __shfl_xor(v, o, 64);
    if (i == 0) out[b] = v * (1.f / 1024.f) + bf[0];
}

extern "C" void kernel_launch(void* const* d_in, const int* in_sizes, int n_in,
                              void* d_out, int out_size, void* d_ws, size_t ws_size,
                              hipStream_t stream)
{
    const float* x      = (const float*)d_in[0];
    const float* Wp     = (const float*)d_in[1];
    const float* bp     = (const float*)d_in[2];
    const float* W_in   = (const float*)d_in[3];
    const float* conv_w = (const float*)d_in[4];
    const float* conv_b = (const float*)d_in[5];
    const float* W_x    = (const float*)d_in[6];
    const float* W_dt   = (const float*)d_in[7];
    const float* b_dt   = (const float*)d_in[8];
    const float* A_log  = (const float*)d_in[9];
    const float* Dp     = (const float*)d_in[10];
    const float* W_out  = (const float*)d_in[11];
    const float* ln_g   = (const float*)d_in[12];
    const float* ln_b   = (const float*)d_in[13];
    const float* Wf     = (const float*)d_in[14];
    const float* bf     = (const float*)d_in[15];

    // ---- workspace layout ----
    char* w = (char*)d_ws;
    float* bufXZ = (float*)w;            w += (size_t)ROWS * 1024 * 4;  // 33.55 MB
    float* bufXD = (float*)w;            w += (size_t)ROWS * 48 * 4;    // 1.57 MB
    u16* xch  = (u16*)w;                 w += (size_t)ROWS * 512 * 2;
    u16* xcl  = (u16*)w;                 w += (size_t)ROWS * 512 * 2;
    u16* hh   = (u16*)w;                 w += (size_t)ROWS * 256 * 2;
    u16* hl   = (u16*)w;                 w += (size_t)ROWS * 256 * 2;
    u16* xih  = (u16*)w;                 w += (size_t)ROWS * 64 * 2;
    u16* xil  = (u16*)w;                 w += (size_t)ROWS * 64 * 2;
    u16* Wpb  = (u16*)w;                 w += (size_t)256 * 64 * 2;
    u16* Wib  = (u16*)w;                 w += (size_t)4 * 1024 * 256 * 2;
    u16* Wxb  = (u16*)w;                 w += (size_t)4 * 64 * 512 * 2;   // padded
    u16* Wob  = (u16*)w;                 w += (size_t)4 * 256 * 512 * 2;
    float* part = (float*)w;             w += 512 * 4;

    dim3 blk(256);

    // one-time conversions (swizzled)
    cvt_x_swz<<<dim3(ROWS * 64 / 256), blk, 0, stream>>>(x, xih, xil);
    cvt_w_swz<<<dim3((CWT + 255) / 256), blk, 0, stream>>>(
        Wp, W_in, W_x, W_out, Wpb, Wib, Wxb, Wob);

    // h = x @ Wp^T + bp  (M=8192, N=Npad=256, K=64) -> swizzled pair
    gemm_sw<1><<<dim3(4, 128), blk, 0, stream>>>(xih, xil, Wpb, bp,
                                                 nullptr, hh, hl,
                                                 ROWS, DMODEL, DMODEL, 64, 0);

    for (int l = 0; l < 4; ++l) {
        const u16* Wil = Wib + (size_t)l * 1024 * 256;
        const u16* Wxl = Wxb + (size_t)l * 64 * 512;
        const u16* Wol = Wob + (size_t)l * 256 * 512;
        const float* cw  = conv_w + (size_t)l * DINNER * 4;
        const float* cb  = conv_b + (size_t)l * DINNER;
        const float* Wdt = W_dt   + (size_t)l * DINNER * DTRANK;
        const float* bdt = b_dt   + (size_t)l * DINNER;
        const float* Al  = A_log  + (size_t)l * DINNER * DSTATE;
        const float* Dl  = Dp     + (size_t)l * DINNER;
        const float* lg  = ln_g   + (size_t)l * DMODEL;
        const float* lb  = ln_b   + (size_t)l * DMODEL;

        // xz = h @ W_in^T  (N=Npad=1024, K=256) -> fp32, wide 64x128 tiles
        gemm_sw128<<<dim3(8, 128), blk, 0, stream>>>(hh, hl, Wil, bufXZ,
                                                     ROWS, 1024, DMODEL, 1024);
        // conv + silu -> xc swizzled pairs (4 rows/thread)
        conv_silu_k<<<dim3(ROWS * DINNER / 4 / 256), blk, 0, stream>>>(
            bufXZ, cw, cb, xch, xcl);
        // x_dbl = xc @ W_x^T  (N=48, K=512) -> fp32 row-major, 256 blocks
        gemm_xdbl<<<dim3(ROWS / 32), blk, 0, stream>>>(xch, xcl, Wxl, bufXD);
        // chunked selective scan (coalesced staging + group-XOR swizzle)
        scan_k<<<dim3(512), dim3(512), 0, stream>>>(xch, xcl, bufXD, bufXZ,
                                                    Al, Dl, Wdt, bdt);
        // out = LN(y @ W_out^T) -> h swizzled pairs, fused (no bufO)
        gemm_out_ln<<<dim3(ROWS / 16), blk, 0, stream>>>(xch, xcl, Wol,
                                                         lg, lb, hh, hl);
    }

    final1_k<<<dim3(512), blk, 0, stream>>>(hh, hl, Wf, part);
    final2_k<<<dim3(1), dim3(512), 0, stream>>>(part, bf, (float*)d_out);

    (void)in_sizes; (void)n_in; (void)out_size; (void)ws_size;
}

// Round 14
// 521.583 us; speedup vs baseline: 1.4898x; 1.0117x over previous
//
#include <hip/hip_runtime.h>
#include <hip/hip_bf16.h>
#include <math.h>

#define SEQ_LEN 1024
#define BATCH_N 8
#define DMODEL 256
#define DINNER 512
#define DSTATE 16
#define DTRANK 16
#define ROWS (BATCH_N * SEQ_LEN)   // 8192
#define NCHUNK 64
#define CHUNK (SEQ_LEN / NCHUNK)   // 16
#define BD 8                       // d-channels per block (scan)

typedef unsigned short u16;
typedef u16 u16x8 __attribute__((ext_vector_type(8)));
typedef short bf16x8 __attribute__((ext_vector_type(8)));
typedef float f32x4 __attribute__((ext_vector_type(4)));

__device__ __forceinline__ float siluf(float x) { return x / (1.f + expf(-x)); }
__device__ __forceinline__ float softplusf(float x) {
    return fmaxf(x, 0.f) + log1pf(expf(-fabsf(x)));
}
// fast-math variants (scan-only; ~2ulp) — round-5 measured-good (-7.4us).
__device__ __forceinline__ float fexpf(float x) { return __expf(x); }
__device__ __forceinline__ float softplus_fast(float x) {
    return fmaxf(x, 0.f) + __logf(1.f + __expf(-fabsf(x)));
}
__device__ __forceinline__ float silu_fast(float x) {
    return x * __builtin_amdgcn_rcpf(1.f + __expf(-x));
}
__device__ __forceinline__ u16 bf16_rne(float x) {
    unsigned u = __builtin_bit_cast(unsigned, x);
    return (u16)((u + 0x7FFFu + ((u >> 16) & 1u)) >> 16);
}
__device__ __forceinline__ void cvt_hl(float x, u16& h, u16& l) {
    unsigned u = __builtin_bit_cast(unsigned, x);
    unsigned hb = (u + 0x7FFFu + ((u >> 16) & 1u)) >> 16;
    h = (u16)hb;
    float hf = __builtin_bit_cast(float, hb << 16);
    l = bf16_rne(x - hf);
}
__device__ __forceinline__ float pair_f(u16 h, u16 l) {
    return __builtin_bit_cast(float, (unsigned)h << 16) +
           __builtin_bit_cast(float, (unsigned)l << 16);
}
// fragment-swizzled activation address: tensor [R rows][Kc cols] stored as
// [Kc/32][R][32]; elem (row,c) at ((c>>5)*R + row)*32 + (c&31)
__device__ __forceinline__ size_t swa(int R, int row, int c) {
    return ((size_t)(c >> 5) * R + row) * 32 + (c & 31);
}

// weight tensors -> fragment-swizzled single bf16 ([k/32][Npad][32])
// segments: Wp(256x64), W_in 4x(1024x256), W_x 4x(48->64 x 512), W_out 4x(256x512)
#define CWT (16384 + 4 * 262144 + 4 * 32768 + 4 * 131072)   // 1720320
__global__ __launch_bounds__(256) void cvt_w_swz(
    const float* __restrict__ Wp, const float* __restrict__ W_in,
    const float* __restrict__ W_x, const float* __restrict__ W_out,
    u16* __restrict__ Wpb, u16* __restrict__ Wib,
    u16* __restrict__ Wxb, u16* __restrict__ Wob)
{
    long i = (long)blockIdx.x * 256 + threadIdx.x;
    if (i >= CWT) return;
    if (i < 16384) {                       // Wp: N=256 K=64
        int n = (int)(i >> 6), k = (int)(i & 63);
        Wpb[((k >> 5) * 256 + n) * 32 + (k & 31)] = bf16_rne(Wp[n * 64 + k]);
        return;
    }
    i -= 16384;
    if (i < 4 * 262144) {                  // W_in: N=1024 K=256
        int l = (int)(i >> 18), r = (int)(i & 262143);
        int n = r >> 8, k = r & 255;
        Wib[l * 262144 + ((k >> 5) * 1024 + n) * 32 + (k & 31)] =
            bf16_rne(W_in[l * 262144 + n * 256 + k]);
        return;
    }
    i -= 4 * 262144;
    if (i < 4 * 32768) {                   // W_x: N=48 (pad 64) K=512
        int l = (int)(i >> 15), r = (int)(i & 32767);
        int n = r >> 9, k = r & 511;
        float v = (n < 48) ? W_x[l * 48 * 512 + n * 512 + k] : 0.f;
        Wxb[l * 32768 + ((k >> 5) * 64 + n) * 32 + (k & 31)] = bf16_rne(v);
        return;
    }
    i -= 4 * 32768;
    {                                      // W_out: N=256 K=512
        int l = (int)(i >> 17), r = (int)(i & 131071);
        int n = r >> 9, k = r & 511;
        Wob[l * 131072 + ((k >> 5) * 256 + n) * 32 + (k & 31)] =
            bf16_rne(W_out[l * 131072 + n * 512 + k]);
    }
}

// ---------------------------------------------------------------------------
// Round-13: prologue GEMM with FUSED x conversion. M=8192, N=256, K=64.
// Reads fp32 x directly (32B/lane contiguous; 2MB, L2-resident across the
// 4x bn redundancy) and converts A-fragments on the fly with the same cvt_hl
// the old cvt_x_swz used; same hi-then-lo MFMA chain, same k-order, same
// bias add and swizzled-pair epilogue -> bitwise-identical hh/hl.
// Kills the cvt_x_swz dispatch + xih/xil staging round-trip.
// ---------------------------------------------------------------------------
__global__ __launch_bounds__(256) void gemm_proj(
    const float* __restrict__ X,     // [ROWS][64] fp32
    const u16* __restrict__ B,       // Wpb swizzled
    const float* __restrict__ bias,  // bp[256]
    u16* __restrict__ Ch, u16* __restrict__ Cl)
{
    const int tid  = threadIdx.x;
    const int wave = tid >> 6, lane = tid & 63;
    const int bm   = blockIdx.y * 64, bn = blockIdx.x * 64;
    const int wm   = (wave >> 1) * 32, wn = (wave & 1) * 32;
    const int fr   = lane & 15, quad = lane >> 4;

    f32x4 acc[2][2];
#pragma unroll
    for (int i = 0; i < 2; i++)
#pragma unroll
        for (int j = 0; j < 2; j++) acc[i][j] = (f32x4){0.f, 0.f, 0.f, 0.f};

    const int r0a = bm + wm + fr;
    const int r1a = r0a + 16;
    const size_t b0 = (size_t)(bn + wn + fr) * 32 + quad * 8;
    const size_t b1 = b0 + 16 * 32;
    const size_t bstep = (size_t)DMODEL * 32;

    const u16* pb = B;
#pragma unroll
    for (int k0 = 0; k0 < 64; k0 += 32) {
        bf16x8 ah0, al0, ah1, al1;
        const float* xa0 = X + (size_t)r0a * 64 + k0 + quad * 8;
        const float* xa1 = X + (size_t)r1a * 64 + k0 + quad * 8;
#pragma unroll
        for (int i = 0; i < 8; i++) {
            u16 h, l;
            cvt_hl(xa0[i], h, l);
            ah0[i] = (short)h; al0[i] = (short)l;
            cvt_hl(xa1[i], h, l);
            ah1[i] = (short)h; al1[i] = (short)l;
        }
        bf16x8 bv0 = *(const bf16x8*)(pb + b0);
        bf16x8 bv1 = *(const bf16x8*)(pb + b1);
        acc[0][0] = __builtin_amdgcn_mfma_f32_16x16x32_bf16(ah0, bv0, acc[0][0], 0, 0, 0);
        acc[0][0] = __builtin_amdgcn_mfma_f32_16x16x32_bf16(al0, bv0, acc[0][0], 0, 0, 0);
        acc[0][1] = __builtin_amdgcn_mfma_f32_16x16x32_bf16(ah0, bv1, acc[0][1], 0, 0, 0);
        acc[0][1] = __builtin_amdgcn_mfma_f32_16x16x32_bf16(al0, bv1, acc[0][1], 0, 0, 0);
        acc[1][0] = __builtin_amdgcn_mfma_f32_16x16x32_bf16(ah1, bv0, acc[1][0], 0, 0, 0);
        acc[1][0] = __builtin_amdgcn_mfma_f32_16x16x32_bf16(al1, bv0, acc[1][0], 0, 0, 0);
        acc[1][1] = __builtin_amdgcn_mfma_f32_16x16x32_bf16(ah1, bv1, acc[1][1], 0, 0, 0);
        acc[1][1] = __builtin_amdgcn_mfma_f32_16x16x32_bf16(al1, bv1, acc[1][1], 0, 0, 0);
        pb += bstep;
    }

    // epilogue: bias + swizzled pair C (N=256 full, no bounds check)
#pragma unroll
    for (int i = 0; i < 2; i++) {
        const int r0 = bm + wm + 16 * i + quad * 4;
#pragma unroll
        for (int reg = 0; reg < 4; reg++) {
            const int row = r0 + reg;
#pragma unroll
            for (int j = 0; j < 2; j++) {
                const int col = bn + wn + 16 * j + fr;
                float v = acc[i][j][reg] + bias[col];
                u16 h, l;
                cvt_hl(v, h, l);
                size_t sw = swa(ROWS, row, col);
                Ch[sw] = h;
                Cl[sw] = l;
            }
        }
    }
}

// ---------------------------------------------------------------------------
// Wide variant: 64x128 block (4 waves 2x2, each 32x64 = 2x4 frags).
// ---------------------------------------------------------------------------
__global__ __launch_bounds__(256) void gemm_sw128(
    const u16* __restrict__ Ah, const u16* __restrict__ Al,
    const u16* __restrict__ B, float* __restrict__ C,
    int M, int Npad, int K, int ldc)
{
    const int tid  = threadIdx.x;
    const int wave = tid >> 6, lane = tid & 63;
    const int bm   = blockIdx.y * 64, bn = blockIdx.x * 128;
    const int wm   = (wave >> 1) * 32, wn = (wave & 1) * 64;
    const int fr   = lane & 15, quad = lane >> 4;

    f32x4 acc[2][4];
#pragma unroll
    for (int i = 0; i < 2; i++)
#pragma unroll
        for (int j = 0; j < 4; j++) acc[i][j] = (f32x4){0.f, 0.f, 0.f, 0.f};

    const size_t a0 = (size_t)(bm + wm + fr) * 32 + quad * 8;
    const size_t a1 = a0 + 16 * 32;
    size_t bofs[4];
#pragma unroll
    for (int j = 0; j < 4; j++)
        bofs[j] = (size_t)(bn + wn + 16 * j + fr) * 32 + quad * 8;
    const size_t astep = (size_t)M * 32;
    const size_t bstep = (size_t)Npad * 32;

    const u16* pah = Ah;
    const u16* pal = Al;
    const u16* pb  = B;
    for (int k0 = 0; k0 < K; k0 += 32) {
        bf16x8 ah0 = *(const bf16x8*)(pah + a0);
        bf16x8 ah1 = *(const bf16x8*)(pah + a1);
        bf16x8 al0 = *(const bf16x8*)(pal + a0);
        bf16x8 al1 = *(const bf16x8*)(pal + a1);
        bf16x8 bv[4];
#pragma unroll
        for (int j = 0; j < 4; j++) bv[j] = *(const bf16x8*)(pb + bofs[j]);
#pragma unroll
        for (int j = 0; j < 4; j++) {
            acc[0][j] = __builtin_amdgcn_mfma_f32_16x16x32_bf16(ah0, bv[j], acc[0][j], 0, 0, 0);
            acc[0][j] = __builtin_amdgcn_mfma_f32_16x16x32_bf16(al0, bv[j], acc[0][j], 0, 0, 0);
            acc[1][j] = __builtin_amdgcn_mfma_f32_16x16x32_bf16(ah1, bv[j], acc[1][j], 0, 0, 0);
            acc[1][j] = __builtin_amdgcn_mfma_f32_16x16x32_bf16(al1, bv[j], acc[1][j], 0, 0, 0);
        }
        pah += astep; pal += astep; pb += bstep;
    }

#pragma unroll
    for (int i = 0; i < 2; i++) {
        const int r0 = bm + wm + 16 * i + quad * 4;
#pragma unroll
        for (int reg = 0; reg < 4; reg++) {
            float* crow = C + (size_t)(r0 + reg) * ldc;
#pragma unroll
            for (int j = 0; j < 4; j++)
                crow[bn + wn + 16 * j + fr] = acc[i][j][reg];
        }
    }
}

// ---------------------------------------------------------------------------
// xdbl GEMM specialization (round-7 measured-good): M=8192, N=48 (Npad=64),
// K=512; 32rx64c blocks, grid 256.
// ---------------------------------------------------------------------------
__global__ __launch_bounds__(256) void gemm_xdbl(
    const u16* __restrict__ Ah, const u16* __restrict__ Al,
    const u16* __restrict__ B, float* __restrict__ C)
{
    const int tid  = threadIdx.x;
    const int wave = tid >> 6, lane = tid & 63;
    const int bm   = blockIdx.x * 32;
    const int wr   = (wave >> 1) * 16;    // row-half within the 32-row tile
    const int wc   = (wave & 1) * 32;     // col-half within the 64-col tile
    const int fr   = lane & 15, quad = lane >> 4;

    f32x4 acc[2];
    acc[0] = (f32x4){0.f, 0.f, 0.f, 0.f};
    acc[1] = (f32x4){0.f, 0.f, 0.f, 0.f};

    const size_t a0 = (size_t)(bm + wr + fr) * 32 + quad * 8;
    const size_t b0 = (size_t)(wc + fr) * 32 + quad * 8;
    const size_t b1 = b0 + 16 * 32;
    const size_t astep = (size_t)ROWS * 32;
    const size_t bstep = (size_t)64 * 32;

    const u16* pah = Ah;
    const u16* pal = Al;
    const u16* pb  = B;
#pragma unroll 4
    for (int k0 = 0; k0 < DINNER; k0 += 32) {
        bf16x8 ah = *(const bf16x8*)(pah + a0);
        bf16x8 al = *(const bf16x8*)(pal + a0);
        bf16x8 bv0 = *(const bf16x8*)(pb + b0);
        bf16x8 bv1 = *(const bf16x8*)(pb + b1);
        acc[0] = __builtin_amdgcn_mfma_f32_16x16x32_bf16(ah, bv0, acc[0], 0, 0, 0);
        acc[0] = __builtin_amdgcn_mfma_f32_16x16x32_bf16(al, bv0, acc[0], 0, 0, 0);
        acc[1] = __builtin_amdgcn_mfma_f32_16x16x32_bf16(ah, bv1, acc[1], 0, 0, 0);
        acc[1] = __builtin_amdgcn_mfma_f32_16x16x32_bf16(al, bv1, acc[1], 0, 0, 0);
        pah += astep; pal += astep; pb += bstep;
    }

    const int r0 = bm + wr + quad * 4;
#pragma unroll
    for (int reg = 0; reg < 4; reg++) {
        const int row = r0 + reg;
#pragma unroll
        for (int j = 0; j < 2; j++) {
            const int col = wc + 16 * j + fr;
            if (col < 48) C[(size_t)row * 48 + col] = acc[j][reg];
        }
    }
}

// ---------------------------------------------------------------------------
// Round-8: W_out GEMM + LayerNorm FUSED (measured-good).
// ---------------------------------------------------------------------------
__global__ __launch_bounds__(256) void gemm_out_ln(
    const u16* __restrict__ Ah, const u16* __restrict__ Al,
    const u16* __restrict__ B,
    const float* __restrict__ g, const float* __restrict__ b2,
    u16* __restrict__ Yh, u16* __restrict__ Yl)
{
    const int tid  = threadIdx.x;
    const int wave = tid >> 6, lane = tid & 63;
    const int bm   = blockIdx.x * 16;
    const int wc   = wave * 64;            // each wave: 64 cols of all 16 rows
    const int fr   = lane & 15, quad = lane >> 4;

    __shared__ float gb[512];              // g[0..255], b[256..511]
    __shared__ float redS[4][16];          // [wave][quad*4+reg] partial sums
    __shared__ float redQ[4][16];
    if (tid < 256) { gb[tid] = g[tid]; gb[256 + tid] = b2[tid]; }

    f32x4 acc[4];
#pragma unroll
    for (int j = 0; j < 4; j++) acc[j] = (f32x4){0.f, 0.f, 0.f, 0.f};

    const size_t a0 = (size_t)(bm + fr) * 32 + quad * 8;
    size_t bofs[4];
#pragma unroll
    for (int j = 0; j < 4; j++)
        bofs[j] = (size_t)(wc + 16 * j + fr) * 32 + quad * 8;
    const size_t astep = (size_t)ROWS * 32;
    const size_t bstep = (size_t)DMODEL * 32;

    const u16* pah = Ah;
    const u16* pal = Al;
    const u16* pb  = B;
#pragma unroll 2
    for (int k0 = 0; k0 < DINNER; k0 += 32) {
        bf16x8 ah = *(const bf16x8*)(pah + a0);
        bf16x8 al = *(const bf16x8*)(pal + a0);
        bf16x8 bv[4];
#pragma unroll
        for (int j = 0; j < 4; j++) bv[j] = *(const bf16x8*)(pb + bofs[j]);
#pragma unroll
        for (int j = 0; j < 4; j++) {
            acc[j] = __builtin_amdgcn_mfma_f32_16x16x32_bf16(ah, bv[j], acc[j], 0, 0, 0);
            acc[j] = __builtin_amdgcn_mfma_f32_16x16x32_bf16(al, bv[j], acc[j], 0, 0, 0);
        }
        pah += astep; pal += astep; pb += bstep;
    }

    // ---- LN reduction ----
    float s[4], q[4];
#pragma unroll
    for (int reg = 0; reg < 4; reg++) {
        float ss = 0.f, qq = 0.f;
#pragma unroll
        for (int j = 0; j < 4; j++) {
            float v = acc[j][reg];
            ss += v;
            qq = fmaf(v, v, qq);
        }
        s[reg] = ss; q[reg] = qq;
    }
#pragma unroll
    for (int o = 1; o < 16; o <<= 1) {
#pragma unroll
        for (int reg = 0; reg < 4; reg++) {
            s[reg] += __shfl_xor(s[reg], o, 64);
            q[reg] += __shfl_xor(q[reg], o, 64);
        }
    }
    __syncthreads();
    if (fr == 0) {
#pragma unroll
        for (int reg = 0; reg < 4; reg++) {
            redS[wave][quad * 4 + reg] = s[reg];
            redQ[wave][quad * 4 + reg] = q[reg];
        }
    }
    __syncthreads();

#pragma unroll
    for (int reg = 0; reg < 4; reg++) {
        const int rl = quad * 4 + reg;
        const int row = bm + rl;
        float S = (redS[0][rl] + redS[1][rl]) + (redS[2][rl] + redS[3][rl]);
        float Q = (redQ[0][rl] + redQ[1][rl]) + (redQ[2][rl] + redQ[3][rl]);
        float mean = S * (1.f / 256.f);
        float var  = Q * (1.f / 256.f) - mean * mean;
        float inv  = rsqrtf(var + 1e-5f);
#pragma unroll
        for (int j = 0; j < 4; j++) {
            const int col = wc + 16 * j + fr;
            float o = (acc[j][reg] - mean) * inv * gb[col] + gb[256 + col];
            u16 h, l;
            cvt_hl(o, h, l);
            size_t sw = swa(ROWS, row, col);
            Yh[sw] = h;
            Yl[sw] = l;
        }
    }
}

// causal depthwise conv (k=4) + bias + silu -> swizzled bf16 pair xc.
// Round-7: 4 rows/thread sliding window (measured-good).
__global__ __launch_bounds__(256) void conv_silu_k(
    const float* __restrict__ xz, const float* __restrict__ cw,
    const float* __restrict__ cb, u16* __restrict__ xch, u16* __restrict__ xcl)
{
    int idx = blockIdx.x * 256 + threadIdx.x;   // < ROWS*512/4
    int d  = idx & (DINNER - 1);
    int rb = idx >> 9;                          // 0..2047
    int row0 = rb * 4;
    int tb = row0 & (SEQ_LEN - 1);
    float4 w = *(const float4*)(cw + d * 4);
    const float bbv = cb[d];
    const float* p = xz + (size_t)row0 * 1024 + d;
    float xm3 = 0.f, xm2 = 0.f, xm1 = 0.f;
    if (tb >= 4) { xm3 = p[-3 * 1024]; xm2 = p[-2 * 1024]; xm1 = p[-1 * 1024]; }
    float x0 = p[0], x1 = p[1024], x2 = p[2 * 1024], x3 = p[3 * 1024];
    float o[4];
    float a;
    a = bbv; a = fmaf(xm3, w.x, a); a = fmaf(xm2, w.y, a); a = fmaf(xm1, w.z, a); a = fmaf(x0, w.w, a); o[0] = a;
    a = bbv; a = fmaf(xm2, w.x, a); a = fmaf(xm1, w.y, a); a = fmaf(x0, w.z, a);  a = fmaf(x1, w.w, a); o[1] = a;
    a = bbv; a = fmaf(xm1, w.x, a); a = fmaf(x0, w.y, a);  a = fmaf(x1, w.z, a);  a = fmaf(x2, w.w, a); o[2] = a;
    a = bbv; a = fmaf(x0, w.x, a);  a = fmaf(x1, w.y, a);  a = fmaf(x2, w.z, a);  a = fmaf(x3, w.w, a); o[3] = a;
    size_t sw = swa(ROWS, row0, d);
#pragma unroll
    for (int i = 0; i < 4; i++) {
        u16 h, l;
        cvt_hl(siluf(o[i]), h, l);
        xch[sw + i * 32] = h;   // consecutive rows: +32 u16 within same kgroup
        xcl[sw + i * 32] = l;
    }
}

// ---------------------------------------------------------------------------
// Chunked selective scan — round-12 state, UNTOUCHED (best measured scan:
// 52.4us; coalesced pre-pass + group-XOR LDS swizzle; conflicts 852K).
// CONFIRMED CONSTRAINTS: unroll 2 only (2x spill); NCHUNK=64/BD=8/grid-512
// geometry only (3x L2 thrash); dt LDS-carry (reg-carry spills).
// ---------------------------------------------------------------------------
__global__ __launch_bounds__(512, 4) void scan_k(
    u16* __restrict__ xch,           // swizzled pair hi; in: xc, out: y
    u16* __restrict__ xcl,           // pair lo
    const float* __restrict__ xdbl,  // [ROWS][48]  (dtr at +0, B at +16, C at +32)
    const float* __restrict__ xz,    // [ROWS][1024]  z at +512
    const float* __restrict__ A_log, // [512][16]
    const float* __restrict__ Dp,    // [512]
    const float* __restrict__ Wdt,   // [512][16]
    const float* __restrict__ bdt)   // [512]
{
    const int tid = threadIdx.x;
    const int dl  = tid & (BD - 1);      // 0..7
    const int ch  = tid >> 3;            // 0..63
    const int b   = blockIdx.x & 7;      // batch -> XCD partition
    const int dg  = blockIdx.x >> 3;     // 0..63
    const int d   = dg * BD + dl;
    const int d0  = dg * BD;             // block's first d

    __shared__ float ldsS[NCHUNK * BD * 16];   // 32 KB (xcv, then S, then h0, then xcv)
    __shared__ float ldsD[CHUNK * 512];        // 32 KB dt stash [t][tid]
    __shared__ float ldsT[NCHUNK * BD];        // 2 KB  per-(chunk,d) sdt

    // per-thread dt weights (one-time 64B, shared across the wave's 8 d's)
    float wv[16];
#pragma unroll
    for (int i = 0; i < 16; i += 4) *(float4*)&wv[i] = *(const float4*)(Wdt + d * 16 + i);
    const float bb = bdt[d];

    bool pow_ok = true;
#pragma unroll
    for (int n = 0; n < 16; n++) {
        float An = -expf(A_log[d * 16 + n]);
        pow_ok = pow_ok && (fabsf(An + (float)(n + 1)) <= 1e-3f * (float)(n + 1));
    }
    const int t0 = b * SEQ_LEN + ch * CHUNK;
    const int base = (ch * BD + dl) * 16;    // == tid*16
    const size_t xcb = ((size_t)(d >> 5) * ROWS) * 32 + (d & 31);  // + row*32

    // base global index for the block's 8-d xc segment of row r (in batch b):
    const size_t gseg = ((size_t)(d0 >> 5) * ROWS + (size_t)b * SEQ_LEN) * 32 + (d0 & 31);

    // ---- Pre-pass 1: cooperative xc -> LDS (f32); coalesced global reads,
    //      group-XOR-swizzled LDS writes (16-way -> 4-way conflict) ----
#pragma unroll
    for (int rr = 0; rr < 2; ++rr) {
        const int r  = tid + rr * 512;           // 0..1023, lane-consecutive
        const int t_ = r & 15;
        const int c_ = r >> 4;                   // 0..63
        const size_t gi = gseg + (size_t)r * 32;
        u16x8 hv = *(const u16x8*)(xch + gi);
        u16x8 lv = *(const u16x8*)(xcl + gi);
        float* dst = ldsS + t_ * 512 + (c_ ^ (t_ & 3)) * 8;
#pragma unroll
        for (int i = 0; i < 8; i++) dst[i] = pair_f(hv[i], lv[i]);
    }
    __syncthreads();

    // ---- Phase A ----
    float S[16];
#pragma unroll
    for (int n = 0; n < 16; n++) S[n] = 0.f;
    float sdt = 0.f;
#pragma unroll 2
    for (int t = 0; t < CHUNK; ++t) {
        const size_t row = (size_t)(t0 + t);
        const float* xr = xdbl + row * 48;
        float qv[16], Bv[16];
#pragma unroll
        for (int i = 0; i < 16; i += 4) *(float4*)&qv[i] = *(const float4*)(xr + i);
#pragma unroll
        for (int i = 0; i < 16; i += 4) *(float4*)&Bv[i] = *(const float4*)(xr + 16 + i);
        float xcv = ldsS[t * 512 + (ch ^ (t & 3)) * 8 + dl];
        // tree-reduced dot (depth ~5 instead of 16-deep serial fmaf chain)
        float s8[8];
#pragma unroll
        for (int i = 0; i < 8; i++) s8[i] = fmaf(qv[i], wv[i], qv[i + 8] * wv[i + 8]);
        float s4_0 = s8[0] + s8[4], s4_1 = s8[1] + s8[5];
        float s4_2 = s8[2] + s8[6], s4_3 = s8[3] + s8[7];
        float dot = bb + ((s4_0 + s4_2) + (s4_1 + s4_3));
        float dtv = softplus_fast(dot);
        ldsD[t * 512 + tid] = dtv;           // stash for phase C
        sdt += dtv;
        float u = dtv * xcv;
        float p[16];
        if (pow_ok) {
            float e1 = fexpf(-dtv);
            p[0] = e1;
#pragma unroll
            for (int n = 1; n < 8; n++) p[n] = p[n - 1] * e1;
            float e8 = p[7];
#pragma unroll
            for (int n = 8; n < 16; n++) p[n] = p[n - 8] * e8;
        } else {
#pragma unroll
            for (int n = 0; n < 16; n++)
                p[n] = exp2f(dtv * (-expf(A_log[d * 16 + n])) * 1.44269504f);
        }
#pragma unroll
        for (int n = 0; n < 16; n++) S[n] = fmaf(p[n], S[n], u * Bv[n]);
    }
    __syncthreads();   // all xcv reads done before S overwrites ldsS
#pragma unroll
    for (int i = 0; i < 16; i += 4) *(float4*)&ldsS[base + i] = *(float4*)&S[i];
    ldsT[tid] = sdt;
    __syncthreads();

    // ---- Phase B: serial prefix over 64 chunks; Pv recomputed from sdt ----
    if (tid < BD * 16) {
        const int dd = tid >> 4;             // 0..7
        const int nn = tid & 15;
        const float An = -fexpf(A_log[(dg * BD + dd) * 16 + nn]);
        float h0 = 0.f;
#pragma unroll 4
        for (int c = 0; c < NCHUNK; ++c) {
            const int idx = (c * BD + dd) * 16 + nn;
            float sdtc = ldsT[c * BD + dd];
            float Sv = ldsS[idx];
            float Pv = fexpf(sdtc * An);
            ldsS[idx] = h0;
            h0 = fmaf(Pv, h0, Sv);
        }
    }
    __syncthreads();

    // ---- h readback, then Pre-pass 2: refill ldsS with xcv for phase C ----
    float h[16];
#pragma unroll
    for (int i = 0; i < 16; i += 4) *(float4*)&h[i] = *(float4*)&ldsS[base + i];
    __syncthreads();   // h reads done before xcv overwrites ldsS
#pragma unroll
    for (int rr = 0; rr < 2; ++rr) {
        const int r  = tid + rr * 512;
        const int t_ = r & 15;
        const int c_ = r >> 4;
        const size_t gi = gseg + (size_t)r * 32;
        u16x8 hv = *(const u16x8*)(xch + gi);
        u16x8 lv = *(const u16x8*)(xcl + gi);
        float* dst = ldsS + t_ * 512 + (c_ ^ (t_ & 3)) * 8;
#pragma unroll
        for (int i = 0; i < 8; i++) dst[i] = pair_f(hv[i], lv[i]);
    }
    __syncthreads();

    // ---- Phase C ----
    const float Dd = Dp[d];
#pragma unroll 2
    for (int t = 0; t < CHUNK; ++t) {
        const size_t row = (size_t)(t0 + t);
        const float* xr = xdbl + row * 48;
        float Bv[16], Cv[16];
#pragma unroll
        for (int i = 0; i < 16; i += 4) *(float4*)&Bv[i] = *(const float4*)(xr + 16 + i);
#pragma unroll
        for (int i = 0; i < 16; i += 4) *(float4*)&Cv[i] = *(const float4*)(xr + 32 + i);
        float xcv = ldsS[t * 512 + (ch ^ (t & 3)) * 8 + dl];
        float zv  = xz[row * 1024 + 512 + d];
        float dtv = ldsD[t * 512 + tid];     // LDS carry from phase A
        float u = dtv * xcv;
        float p[16];
        if (pow_ok) {
            float e1 = fexpf(-dtv);
            p[0] = e1;
#pragma unroll
            for (int n = 1; n < 8; n++) p[n] = p[n - 1] * e1;
            float e8 = p[7];
#pragma unroll
            for (int n = 8; n < 16; n++) p[n] = p[n - 8] * e8;
        } else {
#pragma unroll
            for (int n = 0; n < 16; n++)
                p[n] = exp2f(dtv * (-expf(A_log[d * 16 + n])) * 1.44269504f);
        }
        float y = 0.f;
#pragma unroll
        for (int n = 0; n < 16; n++) {
            h[n] = fmaf(p[n], h[n], u * Bv[n]);
            y = fmaf(h[n], Cv[n], y);
        }
        y = fmaf(Dd, xcv, y);
        y *= silu_fast(zv);
        u16 yh, yl;
        cvt_hl(y, yh, yl);
        xch[xcb + row * 32] = yh;
        xcl[xcb + row * 32] = yl;
    }
}

// final stage 1: per (b, t-chunk of 16) partial dot with Wf -> part[512]
__global__ __launch_bounds__(256) void final1_k(
    const u16* __restrict__ Hh, const u16* __restrict__ Hl,
    const float* __restrict__ Wf, float* __restrict__ part)
{
    const int b   = blockIdx.x >> 6;     // 0..7
    const int ckt = blockIdx.x & 63;     // 0..63
    const int c   = threadIdx.x;
    const size_t cb = ((size_t)(c >> 5) * ROWS) * 32 + (c & 31);
    const int tbase = b * SEQ_LEN + ckt * 16;
    float s = 0.f;
#pragma unroll 4
    for (int t = 0; t < 16; t++) {
        size_t sw = cb + (size_t)(tbase + t) * 32;
        s += pair_f(Hh[sw], Hl[sw]);
    }
    float v = s * Wf[c];
    int lane = c & 63;
#pragma unroll
    for (int o = 1; o < 64; o <<= 1) v += __shfl_xor(v, o, 64);
    __shared__ float red[4];
    if (lane == 0) red[c >> 6] = v;
    __syncthreads();
    if (c == 0) part[blockIdx.x] = red[0] + red[1] + red[2] + red[3];
}

// final stage 2: combine 64 partials per batch
__global__ __launch_bounds__(512) void final2_k(
    const float* __restrict__ part, const float* __restrict__ bf,
    float* __restrict__ out)
{
    int tid = threadIdx.x;            // 512
    int b = tid >> 6, i = tid & 63;
    float v = part[b * 64 + i];
#pragma unroll
    for (int o = 1; o < 64; o <<= 1) v += __shfl_xor(v, o, 64);
    if (i == 0) out[b] = v * (1.f / 1024.f) + bf[0];
}

extern "C" void kernel_launch(void* const* d_in, const int* in_sizes, int n_in,
                              void* d_out, int out_size, void* d_ws, size_t ws_size,
                              hipStream_t stream)
{
    const float* x      = (const float*)d_in[0];
    const float* Wp     = (const float*)d_in[1];
    const float* bp     = (const float*)d_in[2];
    const float* W_in   = (const float*)d_in[3];
    const float* conv_w = (const float*)d_in[4];
    const float* conv_b = (const float*)d_in[5];
    const float* W_x    = (const float*)d_in[6];
    const float* W_dt   = (const float*)d_in[7];
    const float* b_dt   = (const float*)d_in[8];
    const float* A_log  = (const float*)d_in[9];
    const float* Dp     = (const float*)d_in[10];
    const float* W_out  = (const float*)d_in[11];
    const float* ln_g   = (const float*)d_in[12];
    const float* ln_b   = (const float*)d_in[13];
    const float* Wf     = (const float*)d_in[14];
    const float* bf     = (const float*)d_in[15];

    // ---- workspace layout ----
    char* w = (char*)d_ws;
    float* bufXZ = (float*)w;            w += (size_t)ROWS * 1024 * 4;  // 33.55 MB
    float* bufXD = (float*)w;            w += (size_t)ROWS * 48 * 4;    // 1.57 MB
    u16* xch  = (u16*)w;                 w += (size_t)ROWS * 512 * 2;
    u16* xcl  = (u16*)w;                 w += (size_t)ROWS * 512 * 2;
    u16* hh   = (u16*)w;                 w += (size_t)ROWS * 256 * 2;
    u16* hl   = (u16*)w;                 w += (size_t)ROWS * 256 * 2;
    u16* Wpb  = (u16*)w;                 w += (size_t)256 * 64 * 2;
    u16* Wib  = (u16*)w;                 w += (size_t)4 * 1024 * 256 * 2;
    u16* Wxb  = (u16*)w;                 w += (size_t)4 * 64 * 512 * 2;   // padded
    u16* Wob  = (u16*)w;                 w += (size_t)4 * 256 * 512 * 2;
    float* part = (float*)w;             w += 512 * 4;

    dim3 blk(256);

    // one-time weight conversion (swizzled)
    cvt_w_swz<<<dim3((CWT + 255) / 256), blk, 0, stream>>>(
        Wp, W_in, W_x, W_out, Wpb, Wib, Wxb, Wob);

    // h = x @ Wp^T + bp  (fused fp32-x conversion; M=8192, N=256, K=64)
    gemm_proj<<<dim3(4, 128), blk, 0, stream>>>(x, Wpb, bp, hh, hl);

    for (int l = 0; l < 4; ++l) {
        const u16* Wil = Wib + (size_t)l * 1024 * 256;
        const u16* Wxl = Wxb + (size_t)l * 64 * 512;
        const u16* Wol = Wob + (size_t)l * 256 * 512;
        const float* cw  = conv_w + (size_t)l * DINNER * 4;
        const float* cb  = conv_b + (size_t)l * DINNER;
        const float* Wdt = W_dt   + (size_t)l * DINNER * DTRANK;
        const float* bdt = b_dt   + (size_t)l * DINNER;
        const float* Al  = A_log  + (size_t)l * DINNER * DSTATE;
        const float* Dl  = Dp     + (size_t)l * DINNER;
        const float* lg  = ln_g   + (size_t)l * DMODEL;
        const float* lb  = ln_b   + (size_t)l * DMODEL;

        // xz = h @ W_in^T  (N=Npad=1024, K=256) -> fp32, wide 64x128 tiles
        gemm_sw128<<<dim3(8, 128), blk, 0, stream>>>(hh, hl, Wil, bufXZ,
                                                     ROWS, 1024, DMODEL, 1024);
        // conv + silu -> xc swizzled pairs (4 rows/thread)
        conv_silu_k<<<dim3(ROWS * DINNER / 4 / 256), blk, 0, stream>>>(
            bufXZ, cw, cb, xch, xcl);
        // x_dbl = xc @ W_x^T  (N=48, K=512) -> fp32 row-major, 256 blocks
        gemm_xdbl<<<dim3(ROWS / 32), blk, 0, stream>>>(xch, xcl, Wxl, bufXD);
        // chunked selective scan (r12 best-measured state, untouched)
        scan_k<<<dim3(512), dim3(512), 0, stream>>>(xch, xcl, bufXD, bufXZ,
                                                    Al, Dl, Wdt, bdt);
        // out = LN(y @ W_out^T) -> h swizzled pairs, fused (no bufO)
        gemm_out_ln<<<dim3(ROWS / 16), blk, 0, stream>>>(xch, xcl, Wol,
                                                         lg, lb, hh, hl);
    }

    final1_k<<<dim3(512), blk, 0, stream>>>(hh, hl, Wf, part);
    final2_k<<<dim3(1), dim3(512), 0, stream>>>(part, bf, (float*)d_out);

    (void)in_sizes; (void)n_in; (void)out_size; (void)ws_size;
}

// Round 15
// 519.814 us; speedup vs baseline: 1.4949x; 1.0034x over previous
//
#include <hip/hip_runtime.h>
#include <hip/hip_bf16.h>
#include <math.h>

#define SEQ_LEN 1024
#define BATCH_N 8
#define DMODEL 256
#define DINNER 512
#define DSTATE 16
#define DTRANK 16
#define ROWS (BATCH_N * SEQ_LEN)   // 8192
#define NCHUNK 64
#define CHUNK (SEQ_LEN / NCHUNK)   // 16
#define BD 8                       // d-channels per block (scan)

typedef unsigned short u16;
typedef u16 u16x8 __attribute__((ext_vector_type(8)));
typedef short bf16x8 __attribute__((ext_vector_type(8)));
typedef float f32x4 __attribute__((ext_vector_type(4)));

__device__ __forceinline__ float siluf(float x) { return x / (1.f + expf(-x)); }
__device__ __forceinline__ float softplusf(float x) {
    return fmaxf(x, 0.f) + log1pf(expf(-fabsf(x)));
}
// fast-math variants (scan-only; ~2ulp) — round-5 measured-good (-7.4us).
__device__ __forceinline__ float fexpf(float x) { return __expf(x); }
__device__ __forceinline__ float softplus_fast(float x) {
    return fmaxf(x, 0.f) + __logf(1.f + __expf(-fabsf(x)));
}
__device__ __forceinline__ float silu_fast(float x) {
    return x * __builtin_amdgcn_rcpf(1.f + __expf(-x));
}
__device__ __forceinline__ u16 bf16_rne(float x) {
    unsigned u = __builtin_bit_cast(unsigned, x);
    return (u16)((u + 0x7FFFu + ((u >> 16) & 1u)) >> 16);
}
__device__ __forceinline__ void cvt_hl(float x, u16& h, u16& l) {
    unsigned u = __builtin_bit_cast(unsigned, x);
    unsigned hb = (u + 0x7FFFu + ((u >> 16) & 1u)) >> 16;
    h = (u16)hb;
    float hf = __builtin_bit_cast(float, hb << 16);
    l = bf16_rne(x - hf);
}
__device__ __forceinline__ float pair_f(u16 h, u16 l) {
    return __builtin_bit_cast(float, (unsigned)h << 16) +
           __builtin_bit_cast(float, (unsigned)l << 16);
}
// fragment-swizzled activation address: tensor [R rows][Kc cols] stored as
// [Kc/32][R][32]; elem (row,c) at ((c>>5)*R + row)*32 + (c&31)
__device__ __forceinline__ size_t swa(int R, int row, int c) {
    return ((size_t)(c >> 5) * R + row) * 32 + (c & 31);
}

// weight tensors -> fragment-swizzled single bf16 ([k/32][Npad][32])
// segments: Wp(256x64), W_in 4x(1024x256), W_x 4x(48->64 x 512), W_out 4x(256x512)
#define CWT (16384 + 4 * 262144 + 4 * 32768 + 4 * 131072)   // 1720320
__global__ __launch_bounds__(256) void cvt_w_swz(
    const float* __restrict__ Wp, const float* __restrict__ W_in,
    const float* __restrict__ W_x, const float* __restrict__ W_out,
    u16* __restrict__ Wpb, u16* __restrict__ Wib,
    u16* __restrict__ Wxb, u16* __restrict__ Wob)
{
    long i = (long)blockIdx.x * 256 + threadIdx.x;
    if (i >= CWT) return;
    if (i < 16384) {                       // Wp: N=256 K=64
        int n = (int)(i >> 6), k = (int)(i & 63);
        Wpb[((k >> 5) * 256 + n) * 32 + (k & 31)] = bf16_rne(Wp[n * 64 + k]);
        return;
    }
    i -= 16384;
    if (i < 4 * 262144) {                  // W_in: N=1024 K=256
        int l = (int)(i >> 18), r = (int)(i & 262143);
        int n = r >> 8, k = r & 255;
        Wib[l * 262144 + ((k >> 5) * 1024 + n) * 32 + (k & 31)] =
            bf16_rne(W_in[l * 262144 + n * 256 + k]);
        return;
    }
    i -= 4 * 262144;
    if (i < 4 * 32768) {                   // W_x: N=48 (pad 64) K=512
        int l = (int)(i >> 15), r = (int)(i & 32767);
        int n = r >> 9, k = r & 511;
        float v = (n < 48) ? W_x[l * 48 * 512 + n * 512 + k] : 0.f;
        Wxb[l * 32768 + ((k >> 5) * 64 + n) * 32 + (k & 31)] = bf16_rne(v);
        return;
    }
    i -= 4 * 32768;
    {                                      // W_out: N=256 K=512
        int l = (int)(i >> 17), r = (int)(i & 131071);
        int n = r >> 9, k = r & 511;
        Wob[l * 131072 + ((k >> 5) * 256 + n) * 32 + (k & 31)] =
            bf16_rne(W_out[l * 131072 + n * 512 + k]);
    }
}

// ---------------------------------------------------------------------------
// Round-13: prologue GEMM with FUSED x conversion (measured-good).
// ---------------------------------------------------------------------------
__global__ __launch_bounds__(256) void gemm_proj(
    const float* __restrict__ X,     // [ROWS][64] fp32
    const u16* __restrict__ B,       // Wpb swizzled
    const float* __restrict__ bias,  // bp[256]
    u16* __restrict__ Ch, u16* __restrict__ Cl)
{
    const int tid  = threadIdx.x;
    const int wave = tid >> 6, lane = tid & 63;
    const int bm   = blockIdx.y * 64, bn = blockIdx.x * 64;
    const int wm   = (wave >> 1) * 32, wn = (wave & 1) * 32;
    const int fr   = lane & 15, quad = lane >> 4;

    f32x4 acc[2][2];
#pragma unroll
    for (int i = 0; i < 2; i++)
#pragma unroll
        for (int j = 0; j < 2; j++) acc[i][j] = (f32x4){0.f, 0.f, 0.f, 0.f};

    const int r0a = bm + wm + fr;
    const int r1a = r0a + 16;
    const size_t b0 = (size_t)(bn + wn + fr) * 32 + quad * 8;
    const size_t b1 = b0 + 16 * 32;
    const size_t bstep = (size_t)DMODEL * 32;

    const u16* pb = B;
#pragma unroll
    for (int k0 = 0; k0 < 64; k0 += 32) {
        bf16x8 ah0, al0, ah1, al1;
        const float* xa0 = X + (size_t)r0a * 64 + k0 + quad * 8;
        const float* xa1 = X + (size_t)r1a * 64 + k0 + quad * 8;
#pragma unroll
        for (int i = 0; i < 8; i++) {
            u16 h, l;
            cvt_hl(xa0[i], h, l);
            ah0[i] = (short)h; al0[i] = (short)l;
            cvt_hl(xa1[i], h, l);
            ah1[i] = (short)h; al1[i] = (short)l;
        }
        bf16x8 bv0 = *(const bf16x8*)(pb + b0);
        bf16x8 bv1 = *(const bf16x8*)(pb + b1);
        acc[0][0] = __builtin_amdgcn_mfma_f32_16x16x32_bf16(ah0, bv0, acc[0][0], 0, 0, 0);
        acc[0][0] = __builtin_amdgcn_mfma_f32_16x16x32_bf16(al0, bv0, acc[0][0], 0, 0, 0);
        acc[0][1] = __builtin_amdgcn_mfma_f32_16x16x32_bf16(ah0, bv1, acc[0][1], 0, 0, 0);
        acc[0][1] = __builtin_amdgcn_mfma_f32_16x16x32_bf16(al0, bv1, acc[0][1], 0, 0, 0);
        acc[1][0] = __builtin_amdgcn_mfma_f32_16x16x32_bf16(ah1, bv0, acc[1][0], 0, 0, 0);
        acc[1][0] = __builtin_amdgcn_mfma_f32_16x16x32_bf16(al1, bv0, acc[1][0], 0, 0, 0);
        acc[1][1] = __builtin_amdgcn_mfma_f32_16x16x32_bf16(ah1, bv1, acc[1][1], 0, 0, 0);
        acc[1][1] = __builtin_amdgcn_mfma_f32_16x16x32_bf16(al1, bv1, acc[1][1], 0, 0, 0);
        pb += bstep;
    }

    // epilogue: bias + swizzled pair C (N=256 full, no bounds check)
#pragma unroll
    for (int i = 0; i < 2; i++) {
        const int r0 = bm + wm + 16 * i + quad * 4;
#pragma unroll
        for (int reg = 0; reg < 4; reg++) {
            const int row = r0 + reg;
#pragma unroll
            for (int j = 0; j < 2; j++) {
                const int col = bn + wn + 16 * j + fr;
                float v = acc[i][j][reg] + bias[col];
                u16 h, l;
                cvt_hl(v, h, l);
                size_t sw = swa(ROWS, row, col);
                Ch[sw] = h;
                Cl[sw] = l;
            }
        }
    }
}

// ---------------------------------------------------------------------------
// Wide variant: 64x128 block (4 waves 2x2, each 32x64 = 2x4 frags).
// ---------------------------------------------------------------------------
__global__ __launch_bounds__(256) void gemm_sw128(
    const u16* __restrict__ Ah, const u16* __restrict__ Al,
    const u16* __restrict__ B, float* __restrict__ C,
    int M, int Npad, int K, int ldc)
{
    const int tid  = threadIdx.x;
    const int wave = tid >> 6, lane = tid & 63;
    const int bm   = blockIdx.y * 64, bn = blockIdx.x * 128;
    const int wm   = (wave >> 1) * 32, wn = (wave & 1) * 64;
    const int fr   = lane & 15, quad = lane >> 4;

    f32x4 acc[2][4];
#pragma unroll
    for (int i = 0; i < 2; i++)
#pragma unroll
        for (int j = 0; j < 4; j++) acc[i][j] = (f32x4){0.f, 0.f, 0.f, 0.f};

    const size_t a0 = (size_t)(bm + wm + fr) * 32 + quad * 8;
    const size_t a1 = a0 + 16 * 32;
    size_t bofs[4];
#pragma unroll
    for (int j = 0; j < 4; j++)
        bofs[j] = (size_t)(bn + wn + 16 * j + fr) * 32 + quad * 8;
    const size_t astep = (size_t)M * 32;
    const size_t bstep = (size_t)Npad * 32;

    const u16* pah = Ah;
    const u16* pal = Al;
    const u16* pb  = B;
    for (int k0 = 0; k0 < K; k0 += 32) {
        bf16x8 ah0 = *(const bf16x8*)(pah + a0);
        bf16x8 ah1 = *(const bf16x8*)(pah + a1);
        bf16x8 al0 = *(const bf16x8*)(pal + a0);
        bf16x8 al1 = *(const bf16x8*)(pal + a1);
        bf16x8 bv[4];
#pragma unroll
        for (int j = 0; j < 4; j++) bv[j] = *(const bf16x8*)(pb + bofs[j]);
#pragma unroll
        for (int j = 0; j < 4; j++) {
            acc[0][j] = __builtin_amdgcn_mfma_f32_16x16x32_bf16(ah0, bv[j], acc[0][j], 0, 0, 0);
            acc[0][j] = __builtin_amdgcn_mfma_f32_16x16x32_bf16(al0, bv[j], acc[0][j], 0, 0, 0);
            acc[1][j] = __builtin_amdgcn_mfma_f32_16x16x32_bf16(ah1, bv[j], acc[1][j], 0, 0, 0);
            acc[1][j] = __builtin_amdgcn_mfma_f32_16x16x32_bf16(al1, bv[j], acc[1][j], 0, 0, 0);
        }
        pah += astep; pal += astep; pb += bstep;
    }

#pragma unroll
    for (int i = 0; i < 2; i++) {
        const int r0 = bm + wm + 16 * i + quad * 4;
#pragma unroll
        for (int reg = 0; reg < 4; reg++) {
            float* crow = C + (size_t)(r0 + reg) * ldc;
#pragma unroll
            for (int j = 0; j < 4; j++)
                crow[bn + wn + 16 * j + fr] = acc[i][j][reg];
        }
    }
}

// ---------------------------------------------------------------------------
// xdbl GEMM specialization (round-7 measured-good): M=8192, N=48 (Npad=64),
// K=512; 32rx64c blocks, grid 256.
// ---------------------------------------------------------------------------
__global__ __launch_bounds__(256) void gemm_xdbl(
    const u16* __restrict__ Ah, const u16* __restrict__ Al,
    const u16* __restrict__ B, float* __restrict__ C)
{
    const int tid  = threadIdx.x;
    const int wave = tid >> 6, lane = tid & 63;
    const int bm   = blockIdx.x * 32;
    const int wr   = (wave >> 1) * 16;    // row-half within the 32-row tile
    const int wc   = (wave & 1) * 32;     // col-half within the 64-col tile
    const int fr   = lane & 15, quad = lane >> 4;

    f32x4 acc[2];
    acc[0] = (f32x4){0.f, 0.f, 0.f, 0.f};
    acc[1] = (f32x4){0.f, 0.f, 0.f, 0.f};

    const size_t a0 = (size_t)(bm + wr + fr) * 32 + quad * 8;
    const size_t b0 = (size_t)(wc + fr) * 32 + quad * 8;
    const size_t b1 = b0 + 16 * 32;
    const size_t astep = (size_t)ROWS * 32;
    const size_t bstep = (size_t)64 * 32;

    const u16* pah = Ah;
    const u16* pal = Al;
    const u16* pb  = B;
#pragma unroll 4
    for (int k0 = 0; k0 < DINNER; k0 += 32) {
        bf16x8 ah = *(const bf16x8*)(pah + a0);
        bf16x8 al = *(const bf16x8*)(pal + a0);
        bf16x8 bv0 = *(const bf16x8*)(pb + b0);
        bf16x8 bv1 = *(const bf16x8*)(pb + b1);
        acc[0] = __builtin_amdgcn_mfma_f32_16x16x32_bf16(ah, bv0, acc[0], 0, 0, 0);
        acc[0] = __builtin_amdgcn_mfma_f32_16x16x32_bf16(al, bv0, acc[0], 0, 0, 0);
        acc[1] = __builtin_amdgcn_mfma_f32_16x16x32_bf16(ah, bv1, acc[1], 0, 0, 0);
        acc[1] = __builtin_amdgcn_mfma_f32_16x16x32_bf16(al, bv1, acc[1], 0, 0, 0);
        pah += astep; pal += astep; pb += bstep;
    }

    const int r0 = bm + wr + quad * 4;
#pragma unroll
    for (int reg = 0; reg < 4; reg++) {
        const int row = r0 + reg;
#pragma unroll
        for (int j = 0; j < 2; j++) {
            const int col = wc + 16 * j + fr;
            if (col < 48) C[(size_t)row * 48 + col] = acc[j][reg];
        }
    }
}

// ---------------------------------------------------------------------------
// Round-8 fused W_out GEMM + LayerNorm; round-14: optional fused final-pool
// (Wf != nullptr on the LAST layer only). Each lane accumulates o*Wf[col]
// over its 16 pre-quantization outputs; 64-lane shfl reduce + 4-wave LDS
// combine -> part[blockIdx.x]. Index identity: blockIdx.x = row/16
// = b*64 + t-chunk == final1_k's part index, so final2_k is unchanged.
// Kills the final1_k dispatch + its 8.4MB pair re-read.
// ---------------------------------------------------------------------------
__global__ __launch_bounds__(256) void gemm_out_ln(
    const u16* __restrict__ Ah, const u16* __restrict__ Al,
    const u16* __restrict__ B,
    const float* __restrict__ g, const float* __restrict__ b2,
    u16* __restrict__ Yh, u16* __restrict__ Yl,
    const float* __restrict__ Wf, float* __restrict__ part)
{
    const int tid  = threadIdx.x;
    const int wave = tid >> 6, lane = tid & 63;
    const int bm   = blockIdx.x * 16;
    const int wc   = wave * 64;            // each wave: 64 cols of all 16 rows
    const int fr   = lane & 15, quad = lane >> 4;

    __shared__ float gb[512];              // g[0..255], b[256..511]
    __shared__ float redS[4][16];          // [wave][quad*4+reg] partial sums
    __shared__ float redQ[4][16];
    if (tid < 256) { gb[tid] = g[tid]; gb[256 + tid] = b2[tid]; }

    f32x4 acc[4];
#pragma unroll
    for (int j = 0; j < 4; j++) acc[j] = (f32x4){0.f, 0.f, 0.f, 0.f};

    const size_t a0 = (size_t)(bm + fr) * 32 + quad * 8;
    size_t bofs[4];
#pragma unroll
    for (int j = 0; j < 4; j++)
        bofs[j] = (size_t)(wc + 16 * j + fr) * 32 + quad * 8;
    const size_t astep = (size_t)ROWS * 32;
    const size_t bstep = (size_t)DMODEL * 32;

    const u16* pah = Ah;
    const u16* pal = Al;
    const u16* pb  = B;
#pragma unroll 2
    for (int k0 = 0; k0 < DINNER; k0 += 32) {
        bf16x8 ah = *(const bf16x8*)(pah + a0);
        bf16x8 al = *(const bf16x8*)(pal + a0);
        bf16x8 bv[4];
#pragma unroll
        for (int j = 0; j < 4; j++) bv[j] = *(const bf16x8*)(pb + bofs[j]);
#pragma unroll
        for (int j = 0; j < 4; j++) {
            acc[j] = __builtin_amdgcn_mfma_f32_16x16x32_bf16(ah, bv[j], acc[j], 0, 0, 0);
            acc[j] = __builtin_amdgcn_mfma_f32_16x16x32_bf16(al, bv[j], acc[j], 0, 0, 0);
        }
        pah += astep; pal += astep; pb += bstep;
    }

    // ---- LN reduction ----
    float s[4], q[4];
#pragma unroll
    for (int reg = 0; reg < 4; reg++) {
        float ss = 0.f, qq = 0.f;
#pragma unroll
        for (int j = 0; j < 4; j++) {
            float v = acc[j][reg];
            ss += v;
            qq = fmaf(v, v, qq);
        }
        s[reg] = ss; q[reg] = qq;
    }
#pragma unroll
    for (int o = 1; o < 16; o <<= 1) {
#pragma unroll
        for (int reg = 0; reg < 4; reg++) {
            s[reg] += __shfl_xor(s[reg], o, 64);
            q[reg] += __shfl_xor(q[reg], o, 64);
        }
    }
    __syncthreads();
    if (fr == 0) {
#pragma unroll
        for (int reg = 0; reg < 4; reg++) {
            redS[wave][quad * 4 + reg] = s[reg];
            redQ[wave][quad * 4 + reg] = q[reg];
        }
    }
    __syncthreads();

    // per-lane Wf values for its 4 columns (L2-resident, broadcast per fr)
    float wfv[4] = {0.f, 0.f, 0.f, 0.f};
    if (Wf) {
#pragma unroll
        for (int j = 0; j < 4; j++) wfv[j] = Wf[wc + 16 * j + fr];
    }
    float fsum = 0.f;

#pragma unroll
    for (int reg = 0; reg < 4; reg++) {
        const int rl = quad * 4 + reg;
        const int row = bm + rl;
        float S = (redS[0][rl] + redS[1][rl]) + (redS[2][rl] + redS[3][rl]);
        float Q = (redQ[0][rl] + redQ[1][rl]) + (redQ[2][rl] + redQ[3][rl]);
        float mean = S * (1.f / 256.f);
        float var  = Q * (1.f / 256.f) - mean * mean;
        float inv  = rsqrtf(var + 1e-5f);
#pragma unroll
        for (int j = 0; j < 4; j++) {
            const int col = wc + 16 * j + fr;
            float o = (acc[j][reg] - mean) * inv * gb[col] + gb[256 + col];
            fsum = fmaf(o, wfv[j], fsum);
            u16 h, l;
            cvt_hl(o, h, l);
            size_t sw = swa(ROWS, row, col);
            Yh[sw] = h;
            Yl[sw] = l;
        }
    }

    // ---- fused final pool (last layer only) ----
    if (Wf) {
#pragma unroll
        for (int o = 1; o < 64; o <<= 1) fsum += __shfl_xor(fsum, o, 64);
        __syncthreads();             // redS reads above complete
        if (lane == 0) redS[wave][0] = fsum;
        __syncthreads();
        if (tid == 0)
            part[blockIdx.x] = (redS[0][0] + redS[1][0]) + (redS[2][0] + redS[3][0]);
    }
}

// causal depthwise conv (k=4) + bias + silu -> swizzled bf16 pair xc.
// Round-7: 4 rows/thread sliding window (measured-good).
__global__ __launch_bounds__(256) void conv_silu_k(
    const float* __restrict__ xz, const float* __restrict__ cw,
    const float* __restrict__ cb, u16* __restrict__ xch, u16* __restrict__ xcl)
{
    int idx = blockIdx.x * 256 + threadIdx.x;   // < ROWS*512/4
    int d  = idx & (DINNER - 1);
    int rb = idx >> 9;                          // 0..2047
    int row0 = rb * 4;
    int tb = row0 & (SEQ_LEN - 1);
    float4 w = *(const float4*)(cw + d * 4);
    const float bbv = cb[d];
    const float* p = xz + (size_t)row0 * 1024 + d;
    float xm3 = 0.f, xm2 = 0.f, xm1 = 0.f;
    if (tb >= 4) { xm3 = p[-3 * 1024]; xm2 = p[-2 * 1024]; xm1 = p[-1 * 1024]; }
    float x0 = p[0], x1 = p[1024], x2 = p[2 * 1024], x3 = p[3 * 1024];
    float o[4];
    float a;
    a = bbv; a = fmaf(xm3, w.x, a); a = fmaf(xm2, w.y, a); a = fmaf(xm1, w.z, a); a = fmaf(x0, w.w, a); o[0] = a;
    a = bbv; a = fmaf(xm2, w.x, a); a = fmaf(xm1, w.y, a); a = fmaf(x0, w.z, a);  a = fmaf(x1, w.w, a); o[1] = a;
    a = bbv; a = fmaf(xm1, w.x, a); a = fmaf(x0, w.y, a);  a = fmaf(x1, w.z, a);  a = fmaf(x2, w.w, a); o[2] = a;
    a = bbv; a = fmaf(x0, w.x, a);  a = fmaf(x1, w.y, a);  a = fmaf(x2, w.z, a);  a = fmaf(x3, w.w, a); o[3] = a;
    size_t sw = swa(ROWS, row0, d);
#pragma unroll
    for (int i = 0; i < 4; i++) {
        u16 h, l;
        cvt_hl(siluf(o[i]), h, l);
        xch[sw + i * 32] = h;   // consecutive rows: +32 u16 within same kgroup
        xcl[sw + i * 32] = l;
    }
}

// ---------------------------------------------------------------------------
// Chunked selective scan — round-12 state, UNTOUCHED (best measured scan:
// ~52.4-53.4us; coalesced pre-pass + group-XOR LDS swizzle; conflicts 852K).
// CONFIRMED CONSTRAINTS: unroll 2 only (2x spill); NCHUNK=64/BD=8/grid-512
// geometry only (3x L2 thrash); dt LDS-carry (reg-carry spills).
// ---------------------------------------------------------------------------
__global__ __launch_bounds__(512, 4) void scan_k(
    u16* __restrict__ xch,           // swizzled pair hi; in: xc, out: y
    u16* __restrict__ xcl,           // pair lo
    const float* __restrict__ xdbl,  // [ROWS][48]  (dtr at +0, B at +16, C at +32)
    const float* __restrict__ xz,    // [ROWS][1024]  z at +512
    const float* __restrict__ A_log, // [512][16]
    const float* __restrict__ Dp,    // [512]
    const float* __restrict__ Wdt,   // [512][16]
    const float* __restrict__ bdt)   // [512]
{
    const int tid = threadIdx.x;
    const int dl  = tid & (BD - 1);      // 0..7
    const int ch  = tid >> 3;            // 0..63
    const int b   = blockIdx.x & 7;      // batch -> XCD partition
    const int dg  = blockIdx.x >> 3;     // 0..63
    const int d   = dg * BD + dl;
    const int d0  = dg * BD;             // block's first d

    __shared__ float ldsS[NCHUNK * BD * 16];   // 32 KB (xcv, then S, then h0, then xcv)
    __shared__ float ldsD[CHUNK * 512];        // 32 KB dt stash [t][tid]
    __shared__ float ldsT[NCHUNK * BD];        // 2 KB  per-(chunk,d) sdt

    // per-thread dt weights (one-time 64B, shared across the wave's 8 d's)
    float wv[16];
#pragma unroll
    for (int i = 0; i < 16; i += 4) *(float4*)&wv[i] = *(const float4*)(Wdt + d * 16 + i);
    const float bb = bdt[d];

    bool pow_ok = true;
#pragma unroll
    for (int n = 0; n < 16; n++) {
        float An = -expf(A_log[d * 16 + n]);
        pow_ok = pow_ok && (fabsf(An + (float)(n + 1)) <= 1e-3f * (float)(n + 1));
    }
    const int t0 = b * SEQ_LEN + ch * CHUNK;
    const int base = (ch * BD + dl) * 16;    // == tid*16
    const size_t xcb = ((size_t)(d >> 5) * ROWS) * 32 + (d & 31);  // + row*32

    // base global index for the block's 8-d xc segment of row r (in batch b):
    const size_t gseg = ((size_t)(d0 >> 5) * ROWS + (size_t)b * SEQ_LEN) * 32 + (d0 & 31);

    // ---- Pre-pass 1: cooperative xc -> LDS (f32); coalesced global reads,
    //      group-XOR-swizzled LDS writes (16-way -> 4-way conflict) ----
#pragma unroll
    for (int rr = 0; rr < 2; ++rr) {
        const int r  = tid + rr * 512;           // 0..1023, lane-consecutive
        const int t_ = r & 15;
        const int c_ = r >> 4;                   // 0..63
        const size_t gi = gseg + (size_t)r * 32;
        u16x8 hv = *(const u16x8*)(xch + gi);
        u16x8 lv = *(const u16x8*)(xcl + gi);
        float* dst = ldsS + t_ * 512 + (c_ ^ (t_ & 3)) * 8;
#pragma unroll
        for (int i = 0; i < 8; i++) dst[i] = pair_f(hv[i], lv[i]);
    }
    __syncthreads();

    // ---- Phase A ----
    float S[16];
#pragma unroll
    for (int n = 0; n < 16; n++) S[n] = 0.f;
    float sdt = 0.f;
#pragma unroll 2
    for (int t = 0; t < CHUNK; ++t) {
        const size_t row = (size_t)(t0 + t);
        const float* xr = xdbl + row * 48;
        float qv[16], Bv[16];
#pragma unroll
        for (int i = 0; i < 16; i += 4) *(float4*)&qv[i] = *(const float4*)(xr + i);
#pragma unroll
        for (int i = 0; i < 16; i += 4) *(float4*)&Bv[i] = *(const float4*)(xr + 16 + i);
        float xcv = ldsS[t * 512 + (ch ^ (t & 3)) * 8 + dl];
        // tree-reduced dot (depth ~5 instead of 16-deep serial fmaf chain)
        float s8[8];
#pragma unroll
        for (int i = 0; i < 8; i++) s8[i] = fmaf(qv[i], wv[i], qv[i + 8] * wv[i + 8]);
        float s4_0 = s8[0] + s8[4], s4_1 = s8[1] + s8[5];
        float s4_2 = s8[2] + s8[6], s4_3 = s8[3] + s8[7];
        float dot = bb + ((s4_0 + s4_2) + (s4_1 + s4_3));
        float dtv = softplus_fast(dot);
        ldsD[t * 512 + tid] = dtv;           // stash for phase C
        sdt += dtv;
        float u = dtv * xcv;
        float p[16];
        if (pow_ok) {
            float e1 = fexpf(-dtv);
            p[0] = e1;
#pragma unroll
            for (int n = 1; n < 8; n++) p[n] = p[n - 1] * e1;
            float e8 = p[7];
#pragma unroll
            for (int n = 8; n < 16; n++) p[n] = p[n - 8] * e8;
        } else {
#pragma unroll
            for (int n = 0; n < 16; n++)
                p[n] = exp2f(dtv * (-expf(A_log[d * 16 + n])) * 1.44269504f);
        }
#pragma unroll
        for (int n = 0; n < 16; n++) S[n] = fmaf(p[n], S[n], u * Bv[n]);
    }
    __syncthreads();   // all xcv reads done before S overwrites ldsS
#pragma unroll
    for (int i = 0; i < 16; i += 4) *(float4*)&ldsS[base + i] = *(float4*)&S[i];
    ldsT[tid] = sdt;
    __syncthreads();

    // ---- Phase B: serial prefix over 64 chunks; Pv recomputed from sdt ----
    if (tid < BD * 16) {
        const int dd = tid >> 4;             // 0..7
        const int nn = tid & 15;
        const float An = -fexpf(A_log[(dg * BD + dd) * 16 + nn]);
        float h0 = 0.f;
#pragma unroll 4
        for (int c = 0; c < NCHUNK; ++c) {
            const int idx = (c * BD + dd) * 16 + nn;
            float sdtc = ldsT[c * BD + dd];
            float Sv = ldsS[idx];
            float Pv = fexpf(sdtc * An);
            ldsS[idx] = h0;
            h0 = fmaf(Pv, h0, Sv);
        }
    }
    __syncthreads();

    // ---- h readback, then Pre-pass 2: refill ldsS with xcv for phase C ----
    float h[16];
#pragma unroll
    for (int i = 0; i < 16; i += 4) *(float4*)&h[i] = *(float4*)&ldsS[base + i];
    __syncthreads();   // h reads done before xcv overwrites ldsS
#pragma unroll
    for (int rr = 0; rr < 2; ++rr) {
        const int r  = tid + rr * 512;
        const int t_ = r & 15;
        const int c_ = r >> 4;
        const size_t gi = gseg + (size_t)r * 32;
        u16x8 hv = *(const u16x8*)(xch + gi);
        u16x8 lv = *(const u16x8*)(xcl + gi);
        float* dst = ldsS + t_ * 512 + (c_ ^ (t_ & 3)) * 8;
#pragma unroll
        for (int i = 0; i < 8; i++) dst[i] = pair_f(hv[i], lv[i]);
    }
    __syncthreads();

    // ---- Phase C ----
    const float Dd = Dp[d];
#pragma unroll 2
    for (int t = 0; t < CHUNK; ++t) {
        const size_t row = (size_t)(t0 + t);
        const float* xr = xdbl + row * 48;
        float Bv[16], Cv[16];
#pragma unroll
        for (int i = 0; i < 16; i += 4) *(float4*)&Bv[i] = *(const float4*)(xr + 16 + i);
#pragma unroll
        for (int i = 0; i < 16; i += 4) *(float4*)&Cv[i] = *(const float4*)(xr + 32 + i);
        float xcv = ldsS[t * 512 + (ch ^ (t & 3)) * 8 + dl];
        float zv  = xz[row * 1024 + 512 + d];
        float dtv = ldsD[t * 512 + tid];     // LDS carry from phase A
        float u = dtv * xcv;
        float p[16];
        if (pow_ok) {
            float e1 = fexpf(-dtv);
            p[0] = e1;
#pragma unroll
            for (int n = 1; n < 8; n++) p[n] = p[n - 1] * e1;
            float e8 = p[7];
#pragma unroll
            for (int n = 8; n < 16; n++) p[n] = p[n - 8] * e8;
        } else {
#pragma unroll
            for (int n = 0; n < 16; n++)
                p[n] = exp2f(dtv * (-expf(A_log[d * 16 + n])) * 1.44269504f);
        }
        float y = 0.f;
#pragma unroll
        for (int n = 0; n < 16; n++) {
            h[n] = fmaf(p[n], h[n], u * Bv[n]);
            y = fmaf(h[n], Cv[n], y);
        }
        y = fmaf(Dd, xcv, y);
        y *= silu_fast(zv);
        u16 yh, yl;
        cvt_hl(y, yh, yl);
        xch[xcb + row * 32] = yh;
        xcl[xcb + row * 32] = yl;
    }
}

// final stage 2: combine 64 partials per batch
__global__ __launch_bounds__(512) void final2_k(
    const float* __restrict__ part, const float* __restrict__ bf,
    float* __restrict__ out)
{
    int tid = threadIdx.x;            // 512
    int b = tid >> 6, i = tid & 63;
    float v = part[b * 64 + i];
#pragma unroll
    for (int o = 1; o < 64; o <<= 1) v += __shfl_xor(v, o, 64);
    if (i == 0) out[b] = v * (1.f / 1024.f) + bf[0];
}

extern "C" void kernel_launch(void* const* d_in, const int* in_sizes, int n_in,
                              void* d_out, int out_size, void* d_ws, size_t ws_size,
                              hipStream_t stream)
{
    const float* x      = (const float*)d_in[0];
    const float* Wp     = (const float*)d_in[1];
    const float* bp     = (const float*)d_in[2];
    const float* W_in   = (const float*)d_in[3];
    const float* conv_w = (const float*)d_in[4];
    const float* conv_b = (const float*)d_in[5];
    const float* W_x    = (const float*)d_in[6];
    const float* W_dt   = (const float*)d_in[7];
    const float* b_dt   = (const float*)d_in[8];
    const float* A_log  = (const float*)d_in[9];
    const float* Dp     = (const float*)d_in[10];
    const float* W_out  = (const float*)d_in[11];
    const float* ln_g   = (const float*)d_in[12];
    const float* ln_b   = (const float*)d_in[13];
    const float* Wf     = (const float*)d_in[14];
    const float* bf     = (const float*)d_in[15];

    // ---- workspace layout ----
    char* w = (char*)d_ws;
    float* bufXZ = (float*)w;            w += (size_t)ROWS * 1024 * 4;  // 33.55 MB
    float* bufXD = (float*)w;            w += (size_t)ROWS * 48 * 4;    // 1.57 MB
    u16* xch  = (u16*)w;                 w += (size_t)ROWS * 512 * 2;
    u16* xcl  = (u16*)w;                 w += (size_t)ROWS * 512 * 2;
    u16* hh   = (u16*)w;                 w += (size_t)ROWS * 256 * 2;
    u16* hl   = (u16*)w;                 w += (size_t)ROWS * 256 * 2;
    u16* Wpb  = (u16*)w;                 w += (size_t)256 * 64 * 2;
    u16* Wib  = (u16*)w;                 w += (size_t)4 * 1024 * 256 * 2;
    u16* Wxb  = (u16*)w;                 w += (size_t)4 * 64 * 512 * 2;   // padded
    u16* Wob  = (u16*)w;                 w += (size_t)4 * 256 * 512 * 2;
    float* part = (float*)w;             w += 512 * 4;

    dim3 blk(256);

    // one-time weight conversion (swizzled)
    cvt_w_swz<<<dim3((CWT + 255) / 256), blk, 0, stream>>>(
        Wp, W_in, W_x, W_out, Wpb, Wib, Wxb, Wob);

    // h = x @ Wp^T + bp  (fused fp32-x conversion; M=8192, N=256, K=64)
    gemm_proj<<<dim3(4, 128), blk, 0, stream>>>(x, Wpb, bp, hh, hl);

    for (int l = 0; l < 4; ++l) {
        const u16* Wil = Wib + (size_t)l * 1024 * 256;
        const u16* Wxl = Wxb + (size_t)l * 64 * 512;
        const u16* Wol = Wob + (size_t)l * 256 * 512;
        const float* cw  = conv_w + (size_t)l * DINNER * 4;
        const float* cb  = conv_b + (size_t)l * DINNER;
        const float* Wdt = W_dt   + (size_t)l * DINNER * DTRANK;
        const float* bdt = b_dt   + (size_t)l * DINNER;
        const float* Al  = A_log  + (size_t)l * DINNER * DSTATE;
        const float* Dl  = Dp     + (size_t)l * DINNER;
        const float* lg  = ln_g   + (size_t)l * DMODEL;
        const float* lb  = ln_b   + (size_t)l * DMODEL;

        // xz = h @ W_in^T  (N=Npad=1024, K=256) -> fp32, wide 64x128 tiles
        gemm_sw128<<<dim3(8, 128), blk, 0, stream>>>(hh, hl, Wil, bufXZ,
                                                     ROWS, 1024, DMODEL, 1024);
        // conv + silu -> xc swizzled pairs (4 rows/thread)
        conv_silu_k<<<dim3(ROWS * DINNER / 4 / 256), blk, 0, stream>>>(
            bufXZ, cw, cb, xch, xcl);
        // x_dbl = xc @ W_x^T  (N=48, K=512) -> fp32 row-major, 256 blocks
        gemm_xdbl<<<dim3(ROWS / 32), blk, 0, stream>>>(xch, xcl, Wxl, bufXD);
        // chunked selective scan (r12 best-measured state, untouched)
        scan_k<<<dim3(512), dim3(512), 0, stream>>>(xch, xcl, bufXD, bufXZ,
                                                    Al, Dl, Wdt, bdt);
        // out = LN(y @ W_out^T) -> h swizzled pairs; last layer also emits
        // the pooled classifier partials (fused final1)
        const float* wfArg = (l == 3) ? Wf : nullptr;
        gemm_out_ln<<<dim3(ROWS / 16), blk, 0, stream>>>(xch, xcl, Wol,
                                                         lg, lb, hh, hl,
                                                         wfArg, part);
    }

    final2_k<<<dim3(1), dim3(512), 0, stream>>>(part, bf, (float*)d_out);

    (void)in_sizes; (void)n_in; (void)out_size; (void)ws_size;
}